// Round 2
// baseline (329890.698 us; speedup 1.0000x reference)
//
#include <hip/hip_runtime.h>
#include <hip/hip_bf16.h>
#include <stdint.h>

#define NB 256   // batch
#define NT 512   // time
#define NV 128   // vocab
#define NE 64    // embed
#define NH 256   // hidden

// ---------------- helpers ----------------
__device__ __forceinline__ float lo_bf(unsigned u){ return __uint_as_float(u << 16); }
__device__ __forceinline__ float hi_bf(unsigned u){ return __uint_as_float(u & 0xffff0000u); }
__device__ __forceinline__ unsigned short f2us(float f){
  unsigned u = __float_as_uint(f);
  unsigned r = u + 0x7fffu + ((u >> 16) & 1u);
  return (unsigned short)(r >> 16);
}
__device__ __forceinline__ float sigm(float x){
  return __builtin_amdgcn_rcpf(1.f + __expf(-x));
}
__device__ __forceinline__ float ftanh(float xx){
  float a = fabsf(xx);
  a = fminf(a, 9.f);
  float e = __expf(2.f * a);
  float r = __builtin_amdgcn_rcpf(e + 1.f);
  float t = (e - 1.f) * r;
  return copysignf(t, xx);
}

// 16-workgroup group barrier (monotonic counter, device scope)
__device__ __forceinline__ void groupbar(unsigned* c, unsigned target){
  __threadfence();
  __syncthreads();
  if (threadIdx.x == 0){
    __hip_atomic_fetch_add(c, 1u, __ATOMIC_RELEASE, __HIP_MEMORY_SCOPE_AGENT);
    while (__hip_atomic_load(c, __ATOMIC_ACQUIRE, __HIP_MEMORY_SCOPE_AGENT) < target)
      __builtin_amdgcn_s_sleep(2);
  }
  __syncthreads();
  __threadfence();
}

// ---------------- encoder (persistent, 512 steps, fuses keys_proj) ----------------
// grid 256 WGs: (gb = blk>>4) owns rows [gb*16,+16), (gc = blk&15) owns h-cols [gc*16,+16)
// keys written TRANSPOSED: keys_t[b][k][t]  (bf16)
__global__ __launch_bounds__(256, 1)
void enc_kernel(const int* __restrict__ x, const float* __restrict__ emb,
                const float* __restrict__ Wih, const float* __restrict__ Whh,
                const float* __restrict__ bih, const float* __restrict__ bhh,
                const float* __restrict__ Wk,
                unsigned short* __restrict__ enc_out, unsigned short* __restrict__ keys_t,
                float* __restrict__ g_h, float* __restrict__ g_c,
                unsigned* __restrict__ ctrs)
{
  const int tid = threadIdx.x;
  const int blk = blockIdx.x;
  const int gb = blk >> 4, gc = blk & 15;
  const int r0 = gb * 16, c0 = gc * 16;

  extern __shared__ char smem[];
  float* sWi   = (float*)smem;                 // [64][64]  k-major: sWi[k*64+cj]
  float* sWh   = sWi  + 64*64;                 // [256][64]
  float* sWk   = sWh  + 256*64;                // [16][260]
  float* sBias = sWk  + 16*260;                // [64]
  float* sH    = sBias + 64;                   // [16][256]
  float* sXe   = sH   + 16*256;                // [16][64]
  float* sG    = sXe  + 16*64;                 // [64][17]
  uint8_t* sXi = (uint8_t*)(sG + 64*17);       // [16][512]

  for (int i = tid; i < 64*64; i += 256){
    int cj = i & 63, k = i >> 6;
    int grow = ((cj >> 4) * NH) + c0 + (cj & 15);
    sWi[k*64 + cj] = Wih[grow*NE + k];
  }
  for (int i = tid; i < 256*64; i += 256){
    int cj = i & 63, k = i >> 6;
    int grow = ((cj >> 4) * NH) + c0 + (cj & 15);
    sWh[k*64 + cj] = Whh[grow*NH + k];
  }
  if (tid < 64){
    int grow = ((tid >> 4) * NH) + c0 + (tid & 15);
    sBias[tid] = bih[grow] + bhh[grow];
  }
  for (int i = tid; i < 16*256; i += 256){
    int qc = i >> 8, k = i & 255;
    sWk[qc*260 + k] = Wk[(c0 + qc)*NH + k];
  }
  for (int i = tid; i < 16*512; i += 256){
    int rr = i >> 9;
    sXi[i] = (uint8_t)x[(r0 + rr)*NT + (i & 511)];
  }
  for (int i = tid; i < 16*256; i += 256) sH[i] = 0.f;
  __syncthreads();

  const int r  = tid >> 4;
  const int cq = tid & 15;
  float creg = 0.f;
  unsigned* ctr = ctrs + gb*16;

  for (int t = 0; t < NT; ++t){
    // keys_proj for step t-1 (sH currently holds h_{t-1})
    if (t > 0){
      float kv = 0.f;
      const float4* hv = (const float4*)(sH + r*256);
      const float4* wv = (const float4*)(sWk + cq*260);
      #pragma unroll 8
      for (int k4 = 0; k4 < 64; ++k4){
        float4 a = hv[k4], w = wv[k4];
        kv += a.x*w.x + a.y*w.y + a.z*w.z + a.w*w.w;
      }
      keys_t[((size_t)(r0 + r)*NH + c0 + cq)*NT + (t-1)] = f2us(kv);
    }
    // gather x_t embedding
    {
      int idx = sXi[r*512 + t];
      float4 ev = *(const float4*)(emb + idx*NE + cq*4);
      *(float4*)(sXe + r*64 + cq*4) = ev;
    }
    __syncthreads();
    // gates: thread (r, cq) -> gate cols cq*4..cq*4+3 (of 64)
    {
      float4 acc = *(float4*)&sBias[cq*4];
      #pragma unroll 8
      for (int k = 0; k < NE; ++k){
        float a = sXe[r*64 + k];
        float4 w = *(const float4*)(sWi + k*64 + cq*4);
        acc.x += a*w.x; acc.y += a*w.y; acc.z += a*w.z; acc.w += a*w.w;
      }
      #pragma unroll 8
      for (int k = 0; k < NH; ++k){
        float a = sH[r*256 + k];
        float4 w = *(const float4*)(sWh + k*64 + cq*4);
        acc.x += a*w.x; acc.y += a*w.y; acc.z += a*w.z; acc.w += a*w.w;
      }
      sG[(cq*4 + 0)*17 + r] = acc.x;
      sG[(cq*4 + 1)*17 + r] = acc.y;
      sG[(cq*4 + 2)*17 + r] = acc.z;
      sG[(cq*4 + 3)*17 + r] = acc.w;
    }
    __syncthreads();
    // cell update: thread (r, cq) owns cell (r0+r, c0+cq)
    {
      float gi = sigm (sG[( 0 + cq)*17 + r]);
      float gf = sigm (sG[(16 + cq)*17 + r]);
      float gg = ftanh(sG[(32 + cq)*17 + r]);
      float go = sigm (sG[(48 + cq)*17 + r]);
      float cn = gf*creg + gi*gg;
      float hn = go*ftanh(cn);
      creg = cn;
      g_h[((t+1)&1)*NB*NH + (r0+r)*NH + c0 + cq] = hn;
      enc_out[((size_t)(r0+r)*NT + t)*NH + c0 + cq] = f2us(hn);
    }
    groupbar(ctr, (unsigned)(16*(t+1)));
    // reload full h rows for next step
    {
      const float4* src = (const float4*)(g_h + ((t+1)&1)*NB*NH + r0*NH);
      float4* dst = (float4*)sH;
      #pragma unroll 4
      for (int i = tid; i < 1024; i += 256) dst[i] = src[i];
    }
    __syncthreads();
  }
  // keys for final step from sH = h_{511}
  {
    float kv = 0.f;
    const float4* hv = (const float4*)(sH + r*256);
    const float4* wv = (const float4*)(sWk + cq*260);
    #pragma unroll 8
    for (int k4 = 0; k4 < 64; ++k4){
      float4 a = hv[k4], w = wv[k4];
      kv += a.x*w.x + a.y*w.y + a.z*w.z + a.w*w.w;
    }
    keys_t[((size_t)(r0 + r)*NH + c0 + cq)*NT + (NT-1)] = f2us(kv);
  }
  g_c[(r0 + r)*NH + c0 + cq] = creg;
}

// ---------------- decoder (persistent, 1024 threads, 3 group-barriers/step) ----------------
__global__ __launch_bounds__(1024, 1)
void dec_kernel(const int* __restrict__ x, const float* __restrict__ emb,
                const float* __restrict__ Wq, const float* __restrict__ vvec,
                const float* __restrict__ Wih, const float* __restrict__ Whh,
                const float* __restrict__ bih, const float* __restrict__ bhh,
                const float* __restrict__ Wfc, const float* __restrict__ bfc,
                const unsigned short* __restrict__ enc_out, const unsigned short* __restrict__ keys_t,
                float* __restrict__ g_h, float* __restrict__ g_c,
                float* __restrict__ g_q, float* __restrict__ g_ctx,
                float* __restrict__ logits, float* __restrict__ out_h, float* __restrict__ out_c,
                unsigned* __restrict__ ctrs)
{
  const int tid = threadIdx.x;
  const int blk = blockIdx.x;
  const int gb = blk >> 4, gc = blk & 15;
  const int r0 = gb*16, c0 = gc*16;
  const int ra = blk;              // this WG's attention row (= r0 + gc)

  extern __shared__ char smem[];
  float* sWfc = (float*)smem;            // [8][260] f32
  float* sV   = sWfc + 8*260;            // [256]
  float* sBias= sV + 256;                // [64]
  float* sBfc = sBias + 64;              // [8]
  float* sQ   = sBfc + 8;                // [256]
  float* sRed = sQ + 256;                // [16]
  float* sWp  = sRed + 16;               // [512]
  float* sH   = sWp + 512;               // [16][260] padded
  float* sCtx = sH + 16*260;             // [16][260] padded
  float* sXe  = sCtx + 16*260;           // [16][68] padded
  float* sG   = sXe + 16*68;             // [64][17]
  float* sTMP = sG + 64*17;              // [4096] f32 (16KB) transient
  unsigned short* sWq   = (unsigned short*)(sTMP + 4096); // [16][260] bf16
  unsigned short* sWihd = sWq + 16*260;                   // [320][64] bf16
  unsigned short* sWhhd = sWihd + 320*64;                 // [256][64] bf16
  uint8_t* sXi = (uint8_t*)(sWhhd + 256*64);              // [16][512]

  // ---- load weights / constants ----
  for (int i = tid; i < 16*256; i += 1024){
    int qc = i >> 8, k = i & 255;
    sWq[qc*260 + k] = f2us(Wq[(c0 + qc)*NH + k]);
  }
  for (int i = tid; i < 8*256; i += 1024){
    int vc = i >> 8, k = i & 255;
    sWfc[vc*260 + k] = Wfc[(gc*8 + vc)*NH + k];
  }
  if (tid < 256) sV[tid] = vvec[tid];
  if (tid < 64){
    int grow = ((tid >> 4)*NH) + c0 + (tid & 15);
    sBias[tid] = bih[grow] + bhh[grow];
  }
  if (tid < 8) sBfc[tid] = bfc[gc*8 + tid];
  for (int i = tid; i < 320*64; i += 1024){
    int cj = i & 63, k = i >> 6;
    int grow = ((cj >> 4)*NH) + c0 + (cj & 15);
    sWihd[k*64 + cj] = f2us(Wih[grow*320 + k]);
  }
  for (int i = tid; i < 256*64; i += 1024){
    int cj = i & 63, k = i >> 6;
    int grow = ((cj >> 4)*NH) + c0 + (cj & 15);
    sWhhd[k*64 + cj] = f2us(Whh[grow*NH + k]);
  }
  for (int i = tid; i < 16*512; i += 1024){
    int rr = i >> 9;
    sXi[i] = (uint8_t)x[(r0 + rr)*NT + (i & 511)];
  }
  float creg = 0.f, hlast = 0.f;
  if (tid < 256) creg = g_c[(r0 + (tid>>4))*NH + c0 + (tid&15)];
  unsigned* ctr = ctrs + 256 + gb*16;
  __syncthreads();

  for (int t = 0; t < NT; ++t){
    // ================= Phase Q: load h_{t-1}, q proj, logits[t-1] =================
    {
      int rr = tid >> 6, cc = tid & 63;
      float4 hv4 = ((const float4*)(g_h + r0*NH))[tid];
      *(float4*)(sH + rr*260 + cc*4) = hv4;
    }
    __syncthreads();
    if (tid < 256){
      int r = tid >> 4, cq = tid & 15;
      const uint2*  wq = (const uint2*)(sWq + cq*260);
      const float4* hv = (const float4*)(sH + r*260);
      float qv = 0.f;
      #pragma unroll 8
      for (int k4 = 0; k4 < 64; ++k4){
        float4 a = hv[k4]; uint2 u = wq[k4];
        qv += a.x*lo_bf(u.x) + a.y*hi_bf(u.x) + a.z*lo_bf(u.y) + a.w*hi_bf(u.y);
      }
      g_q[(r0 + r)*NH + c0 + cq] = qv;
    } else if (t > 0 && tid < 384){
      int lt = tid - 256, r = lt >> 3, vc = lt & 7;
      const float4* hv = (const float4*)(sH + r*260);
      const float4* wv = (const float4*)(sWfc + vc*260);
      float lv = sBfc[vc];
      #pragma unroll 8
      for (int k4 = 0; k4 < 64; ++k4){
        float4 a = hv[k4], w = wv[k4];
        lv += a.x*w.x + a.y*w.y + a.z*w.z + a.w*w.w;
      }
      logits[((size_t)(r0 + r)*NT + (t-1))*NV + gc*8 + vc] = lv;
    }
    groupbar(ctr, (unsigned)(48*t + 16));

    // ================= Phase A: attention for row ra =================
    if (tid < 256) sQ[tid] = g_q[ra*NH + tid];
    __syncthreads();
    // energy partials: kh = k-chunk (8 x 32k), sp = 4 s-positions
    {
      const int kh = tid >> 7;       // 0..7 (wave-uniform)
      const int sp = tid & 127;      // 4 positions: s0 = sp*4
      const unsigned short* ktp = keys_t + ((size_t)ra*NH + kh*32)*NT + sp*4;
      float e0=0.f, e1=0.f, e2=0.f, e3=0.f;
      #pragma unroll 8
      for (int kk = 0; kk < 32; ++kk){
        uint2 u = *(const uint2*)(ktp + (size_t)kk*NT);
        float qk = sQ[kh*32 + kk], vk = sV[kh*32 + kk];
        e0 += vk*ftanh(qk + lo_bf(u.x));
        e1 += vk*ftanh(qk + hi_bf(u.x));
        e2 += vk*ftanh(qk + lo_bf(u.y));
        e3 += vk*ftanh(qk + hi_bf(u.y));
      }
      *(float4*)(sTMP + kh*512 + sp*4) = make_float4(e0,e1,e2,e3);
    }
    __syncthreads();
    // combine k-chunks, exp, wave-level denom partials
    if (tid < 512){
      float e = sTMP[tid]        + sTMP[512 + tid]  + sTMP[1024 + tid] + sTMP[1536 + tid]
              + sTMP[2048 + tid] + sTMP[2560 + tid] + sTMP[3072 + tid] + sTMP[3584 + tid];
      float w = (sXi[gc*512 + tid] == 0) ? 0.f : __expf(e);
      sWp[tid] = w;
      float s = w;
      #pragma unroll
      for (int off = 32; off > 0; off >>= 1) s += __shfl_down(s, off, 64);
      if ((tid & 63) == 0) sRed[tid >> 6] = s;
    }
    __syncthreads();
    // context partials: sc = s-chunk (16 x 32s), kc = 4 k-cols
    {
      const int sc = tid >> 6;       // 0..15
      const int kc = tid & 63;       // cols kc*4..+3
      const unsigned short* ep = enc_out + ((size_t)ra*NT + sc*32)*NH + kc*4;
      float a0=0.f, a1=0.f, a2=0.f, a3=0.f;
      #pragma unroll 8
      for (int ss = 0; ss < 32; ++ss){
        float w = sWp[sc*32 + ss];
        uint2 u = *(const uint2*)(ep + (size_t)ss*NH);
        a0 += w*lo_bf(u.x); a1 += w*hi_bf(u.x);
        a2 += w*lo_bf(u.y); a3 += w*hi_bf(u.y);
      }
      *(float4*)(sTMP + sc*256 + kc*4) = make_float4(a0,a1,a2,a3);
    }
    __syncthreads();
    if (tid < 256){
      float den = sRed[0]+sRed[1]+sRed[2]+sRed[3]+sRed[4]+sRed[5]+sRed[6]+sRed[7];
      float rden = (den > 0.f) ? (1.f/den) : 0.f;
      float cs = 0.f;
      #pragma unroll
      for (int p = 0; p < 16; ++p) cs += sTMP[p*256 + tid];
      g_ctx[ra*NH + tid] = cs * rden;
    }
    groupbar(ctr, (unsigned)(48*t + 32));

    // ================= Phase L: LSTM cell (input = [emb_t | ctx]) =================
    {
      int rr = tid >> 6, cc = tid & 63;
      float4 cv = ((const float4*)(g_ctx + r0*NH))[tid];
      *(float4*)(sCtx + rr*260 + cc*4) = cv;
      if (tid < 256){
        int r2 = tid >> 4, cq2 = tid & 15;
        int idx = sXi[r2*512 + t];
        *(float4*)(sXe + r2*68 + cq2*4) = *(const float4*)(emb + idx*NE + cq2*4);
      }
    }
    __syncthreads();
    // gate partials: kseg (4 segments of 144 k) x 256 (r, q4) threads
    {
      const int kseg = tid >> 8;           // 0..3 (wave-uniform)
      const int rq   = tid & 255;
      const int r    = rq >> 4;
      const int q4b  = (rq & 15) * 4;
      float4 acc = make_float4(0.f,0.f,0.f,0.f);
      #define GMAC(AV, WP) { uint2 u_ = *(const uint2*)(WP); float a_ = (AV); \
        acc.x += a_*lo_bf(u_.x); acc.y += a_*hi_bf(u_.x); \
        acc.z += a_*lo_bf(u_.y); acc.w += a_*hi_bf(u_.y); }
      if (kseg == 0){
        #pragma unroll 8
        for (int k = 0; k < 64; ++k)  GMAC(sXe[r*68 + k],        sWihd + k*64 + q4b);
        #pragma unroll 8
        for (int k = 0; k < 80; ++k)  GMAC(sCtx[r*260 + k],      sWihd + (64+k)*64 + q4b);
      } else if (kseg == 1){
        #pragma unroll 8
        for (int k = 80; k < 224; ++k) GMAC(sCtx[r*260 + k],     sWihd + (64+k)*64 + q4b);
      } else if (kseg == 2){
        #pragma unroll 8
        for (int k = 224; k < 256; ++k) GMAC(sCtx[r*260 + k],    sWihd + (64+k)*64 + q4b);
        #pragma unroll 8
        for (int k = 0; k < 112; ++k)  GMAC(sH[r*260 + k],       sWhhd + k*64 + q4b);
      } else {
        #pragma unroll 8
        for (int k = 112; k < 256; ++k) GMAC(sH[r*260 + k],      sWhhd + k*64 + q4b);
      }
      #undef GMAC
      *(float4*)(sTMP + (kseg*256 + rq)*4) = acc;
    }
    __syncthreads();
    if (tid < 256){
      const int r = tid >> 4, q4b = (tid & 15)*4;
      float4 g = *(float4*)(sBias + q4b);
      #pragma unroll
      for (int p = 0; p < 4; ++p){
        float4 pp = *(float4*)(sTMP + (p*256 + tid)*4);
        g.x += pp.x; g.y += pp.y; g.z += pp.z; g.w += pp.w;
      }
      sG[(q4b+0)*17 + r] = g.x;
      sG[(q4b+1)*17 + r] = g.y;
      sG[(q4b+2)*17 + r] = g.z;
      sG[(q4b+3)*17 + r] = g.w;
    }
    __syncthreads();
    if (tid < 256){
      const int r = tid >> 4, cq = tid & 15;
      float gi = sigm (sG[( 0 + cq)*17 + r]);
      float gf = sigm (sG[(16 + cq)*17 + r]);
      float gg = ftanh(sG[(32 + cq)*17 + r]);
      float go = sigm (sG[(48 + cq)*17 + r]);
      float cn = gf*creg + gi*gg;
      hlast = go*ftanh(cn);
      creg = cn;
      g_h[(r0+r)*NH + c0 + cq] = hlast;
    }
    groupbar(ctr, (unsigned)(48*t + 48));
  }

  // final logits (t = 511) + h_f, c_f
  {
    int rr = tid >> 6, cc = tid & 63;
    float4 hv4 = ((const float4*)(g_h + r0*NH))[tid];
    *(float4*)(sH + rr*260 + cc*4) = hv4;
  }
  __syncthreads();
  if (tid >= 256 && tid < 384){
    int lt = tid - 256, r = lt >> 3, vc = lt & 7;
    const float4* hv = (const float4*)(sH + r*260);
    const float4* wv = (const float4*)(sWfc + vc*260);
    float lv = sBfc[vc];
    #pragma unroll 8
    for (int k4 = 0; k4 < 64; ++k4){
      float4 a = hv[k4], w = wv[k4];
      lv += a.x*w.x + a.y*w.y + a.z*w.z + a.w*w.w;
    }
    logits[((size_t)(r0 + r)*NT + (NT-1))*NV + gc*8 + vc] = lv;
  }
  if (tid < 256){
    out_h[(r0 + (tid>>4))*NH + c0 + (tid&15)] = hlast;
    out_c[(r0 + (tid>>4))*NH + c0 + (tid&15)] = creg;
  }
}

// ---------------- launcher ----------------
extern "C" void kernel_launch(void* const* d_in, const int* in_sizes, int n_in,
                              void* d_out, int out_size, void* d_ws, size_t ws_size,
                              hipStream_t stream)
{
  (void)in_sizes; (void)n_in; (void)out_size; (void)ws_size;
  const int*   x    = (const int*)  d_in[0];
  const float* emb  = (const float*)d_in[1];
  const float* Wihe = (const float*)d_in[2];
  const float* Whhe = (const float*)d_in[3];
  const float* bihe = (const float*)d_in[4];
  const float* bhhe = (const float*)d_in[5];
  const float* Wq   = (const float*)d_in[6];
  const float* Wk   = (const float*)d_in[7];
  const float* vv   = (const float*)d_in[8];
  const float* Wihd = (const float*)d_in[9];
  const float* Whhd = (const float*)d_in[10];
  const float* bihd = (const float*)d_in[11];
  const float* bhhd = (const float*)d_in[12];
  const float* Wfc  = (const float*)d_in[13];
  const float* bfc  = (const float*)d_in[14];

  char* ws = (char*)d_ws;
  unsigned* ctrs = (unsigned*)ws;                                 // 8 KB
  unsigned short* enc   = (unsigned short*)(ws + 8192);           // 64 MB (bf16, [B][T][H])
  unsigned short* keyst = (unsigned short*)(ws + 8192 + 67108864);// 64 MB (bf16, [B][H][T])
  float* g_h  = (float*)(ws + 8192 + 2*67108864);                 // 2 * B*H
  float* g_c  = g_h + 2*NB*NH;
  float* g_q  = g_c + NB*NH;
  float* g_ctx= g_q + NB*NH;

  float* out_logits = (float*)d_out;
  float* out_h = out_logits + (size_t)NB*NT*NV;
  float* out_c = out_h + NB*NH;

  hipMemsetAsync(ctrs, 0, 8192, stream);

  const size_t smem_enc = (size_t)(64*64 + 256*64 + 16*260 + 64 + 16*256 + 16*64 + 64*17)*4 + 16*512;
  const size_t smem_dec = (size_t)(8*260 + 256 + 64 + 8 + 256 + 16 + 512
                                   + 16*260 + 16*260 + 16*68 + 64*17 + 4096)*4
                          + (size_t)(16*260 + 320*64 + 256*64)*2 + 16*512;

  enc_kernel<<<dim3(256), dim3(256), smem_enc, stream>>>(
      x, emb, Wihe, Whhe, bihe, bhhe, Wk, enc, keyst, g_h, g_c, ctrs);
  dec_kernel<<<dim3(256), dim3(1024), smem_dec, stream>>>(
      x, emb, Wq, vv, Wihd, Whhd, bihd, bhhd, Wfc, bfc,
      enc, keyst, g_h, g_c, g_q, g_ctx, out_logits, out_h, out_c, ctrs);
}

// Round 3
// 64768.488 us; speedup vs baseline: 5.0934x; 5.0934x over previous
//
#include <hip/hip_runtime.h>
#include <hip/hip_bf16.h>
#include <stdint.h>

#define NB 256   // batch
#define NT 512   // time
#define NV 128   // vocab
#define NE 64    // embed
#define NH 256   // hidden

// ---------------- helpers ----------------
__device__ __forceinline__ float lo_bf(unsigned u){ return __uint_as_float(u << 16); }
__device__ __forceinline__ float hi_bf(unsigned u){ return __uint_as_float(u & 0xffff0000u); }
__device__ __forceinline__ unsigned short f2us(float f){
  unsigned u = __float_as_uint(f);
  unsigned r = u + 0x7fffu + ((u >> 16) & 1u);
  return (unsigned short)(r >> 16);
}
__device__ __forceinline__ float sigm(float x){
  return __builtin_amdgcn_rcpf(1.f + __expf(-x));
}
__device__ __forceinline__ float ftanh(float xx){
  float a = fabsf(xx);
  a = fminf(a, 9.f);
  float e = __expf(2.f * a);
  float r = __builtin_amdgcn_rcpf(e + 1.f);
  float t = (e - 1.f) * r;
  return copysignf(t, xx);
}

// 16-workgroup group barrier (monotonic counter, device scope) — ENCODER ONLY
__device__ __forceinline__ void groupbar(unsigned* c, unsigned target){
  __threadfence();
  __syncthreads();
  if (threadIdx.x == 0){
    __hip_atomic_fetch_add(c, 1u, __ATOMIC_RELEASE, __HIP_MEMORY_SCOPE_AGENT);
    while (__hip_atomic_load(c, __ATOMIC_ACQUIRE, __HIP_MEMORY_SCOPE_AGENT) < target)
      __builtin_amdgcn_s_sleep(2);
  }
  __syncthreads();
  __threadfence();
}

// ---------------- prep: transpose decoder weights to k-major bf16 ----------------
__global__ __launch_bounds__(256, 1)
void prep_kernel(const float* __restrict__ Wq, const float* __restrict__ Wfc,
                 const float* __restrict__ Wih, const float* __restrict__ Whh,
                 unsigned short* __restrict__ WqT, unsigned short* __restrict__ WfcT,
                 unsigned short* __restrict__ WihT, unsigned short* __restrict__ WhhT)
{
  const int blk = blockIdx.x, tid = threadIdx.x;
  if (blk < 256){                       // WqT[k][c], k = blk
    WqT[blk*256 + tid] = f2us(Wq[tid*256 + blk]);
  } else if (blk < 512){                // WfcT[k][v], k = blk-256
    int k = blk - 256;
    if (tid < 128) WfcT[k*128 + tid] = f2us(Wfc[tid*256 + k]);
  } else if (blk < 832){                // WihT[k][g], k = blk-512 (0..319)
    int k = blk - 512;
    #pragma unroll
    for (int j = 0; j < 4; ++j){
      int g = tid + j*256;
      WihT[k*1024 + g] = f2us(Wih[g*320 + k]);
    }
  } else {                              // WhhT[k][g], k = blk-832 (0..255)
    int k = blk - 832;
    #pragma unroll
    for (int j = 0; j < 4; ++j){
      int g = tid + j*256;
      WhhT[k*1024 + g] = f2us(Whh[g*256 + k]);
    }
  }
}

// ---------------- encoder (persistent, 512 steps, fuses keys_proj) ----------------
// unchanged from round 2 (measured ~2ms)
__global__ __launch_bounds__(256, 1)
void enc_kernel(const int* __restrict__ x, const float* __restrict__ emb,
                const float* __restrict__ Wih, const float* __restrict__ Whh,
                const float* __restrict__ bih, const float* __restrict__ bhh,
                const float* __restrict__ Wk,
                unsigned short* __restrict__ enc_out, unsigned short* __restrict__ keys_t,
                float* __restrict__ g_h, float* __restrict__ g_c,
                unsigned* __restrict__ ctrs)
{
  const int tid = threadIdx.x;
  const int blk = blockIdx.x;
  const int gb = blk >> 4, gc = blk & 15;
  const int r0 = gb * 16, c0 = gc * 16;

  extern __shared__ char smem[];
  float* sWi   = (float*)smem;                 // [64][64]
  float* sWh   = sWi  + 64*64;                 // [256][64]
  float* sWk   = sWh  + 256*64;                // [16][260]
  float* sBias = sWk  + 16*260;                // [64]
  float* sH    = sBias + 64;                   // [16][256]
  float* sXe   = sH   + 16*256;                // [16][64]
  float* sG    = sXe  + 16*64;                 // [64][17]
  uint8_t* sXi = (uint8_t*)(sG + 64*17);       // [16][512]

  for (int i = tid; i < 64*64; i += 256){
    int cj = i & 63, k = i >> 6;
    int grow = ((cj >> 4) * NH) + c0 + (cj & 15);
    sWi[k*64 + cj] = Wih[grow*NE + k];
  }
  for (int i = tid; i < 256*64; i += 256){
    int cj = i & 63, k = i >> 6;
    int grow = ((cj >> 4) * NH) + c0 + (cj & 15);
    sWh[k*64 + cj] = Whh[grow*NH + k];
  }
  if (tid < 64){
    int grow = ((tid >> 4) * NH) + c0 + (tid & 15);
    sBias[tid] = bih[grow] + bhh[grow];
  }
  for (int i = tid; i < 16*256; i += 256){
    int qc = i >> 8, k = i & 255;
    sWk[qc*260 + k] = Wk[(c0 + qc)*NH + k];
  }
  for (int i = tid; i < 16*512; i += 256){
    int rr = i >> 9;
    sXi[i] = (uint8_t)x[(r0 + rr)*NT + (i & 511)];
  }
  for (int i = tid; i < 16*256; i += 256) sH[i] = 0.f;
  __syncthreads();

  const int r  = tid >> 4;
  const int cq = tid & 15;
  float creg = 0.f;
  unsigned* ctr = ctrs + gb*16;

  for (int t = 0; t < NT; ++t){
    if (t > 0){
      float kv = 0.f;
      const float4* hv = (const float4*)(sH + r*256);
      const float4* wv = (const float4*)(sWk + cq*260);
      #pragma unroll 8
      for (int k4 = 0; k4 < 64; ++k4){
        float4 a = hv[k4], w = wv[k4];
        kv += a.x*w.x + a.y*w.y + a.z*w.z + a.w*w.w;
      }
      keys_t[((size_t)(r0 + r)*NH + c0 + cq)*NT + (t-1)] = f2us(kv);
    }
    {
      int idx = sXi[r*512 + t];
      float4 ev = *(const float4*)(emb + idx*NE + cq*4);
      *(float4*)(sXe + r*64 + cq*4) = ev;
    }
    __syncthreads();
    {
      float4 acc = *(float4*)&sBias[cq*4];
      #pragma unroll 8
      for (int k = 0; k < NE; ++k){
        float a = sXe[r*64 + k];
        float4 w = *(const float4*)(sWi + k*64 + cq*4);
        acc.x += a*w.x; acc.y += a*w.y; acc.z += a*w.z; acc.w += a*w.w;
      }
      #pragma unroll 8
      for (int k = 0; k < NH; ++k){
        float a = sH[r*256 + k];
        float4 w = *(const float4*)(sWh + k*64 + cq*4);
        acc.x += a*w.x; acc.y += a*w.y; acc.z += a*w.z; acc.w += a*w.w;
      }
      sG[(cq*4 + 0)*17 + r] = acc.x;
      sG[(cq*4 + 1)*17 + r] = acc.y;
      sG[(cq*4 + 2)*17 + r] = acc.z;
      sG[(cq*4 + 3)*17 + r] = acc.w;
    }
    __syncthreads();
    {
      float gi = sigm (sG[( 0 + cq)*17 + r]);
      float gf = sigm (sG[(16 + cq)*17 + r]);
      float gg = ftanh(sG[(32 + cq)*17 + r]);
      float go = sigm (sG[(48 + cq)*17 + r]);
      float cn = gf*creg + gi*gg;
      float hn = go*ftanh(cn);
      creg = cn;
      g_h[((t+1)&1)*NB*NH + (r0+r)*NH + c0 + cq] = hn;
      enc_out[((size_t)(r0+r)*NT + t)*NH + c0 + cq] = f2us(hn);
    }
    groupbar(ctr, (unsigned)(16*(t+1)));
    {
      const float4* src = (const float4*)(g_h + ((t+1)&1)*NB*NH + r0*NH);
      float4* dst = (float4*)sH;
      #pragma unroll 4
      for (int i = tid; i < 1024; i += 256) dst[i] = src[i];
    }
    __syncthreads();
  }
  {
    float kv = 0.f;
    const float4* hv = (const float4*)(sH + r*256);
    const float4* wv = (const float4*)(sWk + cq*260);
    #pragma unroll 8
    for (int k4 = 0; k4 < 64; ++k4){
      float4 a = hv[k4], w = wv[k4];
      kv += a.x*w.x + a.y*w.y + a.z*w.z + a.w*w.w;
    }
    keys_t[((size_t)(r0 + r)*NH + c0 + cq)*NT + (NT-1)] = f2us(kv);
  }
  g_c[(r0 + r)*NH + c0 + cq] = creg;
}

// ---------------- decoder: ONE batch row per WG, fully WG-local, NO global sync ----------------
__global__ __launch_bounds__(512, 1)
void dec_kernel(const int* __restrict__ x, const float* __restrict__ emb,
                const unsigned short* __restrict__ WqT, const float* __restrict__ vvec,
                const unsigned short* __restrict__ WihT, const unsigned short* __restrict__ WhhT,
                const float* __restrict__ bih, const float* __restrict__ bhh,
                const unsigned short* __restrict__ WfcT, const float* __restrict__ bfc,
                const unsigned short* __restrict__ enc_out, const unsigned short* __restrict__ keys_t,
                const float* __restrict__ g_h, const float* __restrict__ g_c,
                float* __restrict__ logits, float* __restrict__ out_h, float* __restrict__ out_c)
{
  const int tid = threadIdx.x;
  const int b   = blockIdx.x;           // this WG's batch row

  __shared__ float sTMP[4096];          // 16KB scratch (partials)
  __shared__ float sWp[512];            // softmax numerators
  __shared__ float sRed[8];
  __shared__ float sQ[256];
  __shared__ float sH[256];
  __shared__ float sCtx[256];
  __shared__ float sXe[64];
  __shared__ float sG[1024];
  __shared__ float sBiasD[1024];
  __shared__ float sBfc[128];
  __shared__ float sV[256];
  __shared__ uint8_t sXi[512];

  // ---- init ----
  for (int i = tid; i < 1024; i += 512) sBiasD[i] = bih[i] + bhh[i];
  if (tid < 128) sBfc[tid] = bfc[tid];
  if (tid < 256){ sV[tid] = vvec[tid]; sH[tid] = g_h[b*NH + tid]; }
  sXi[tid] = (uint8_t)x[b*NT + tid];
  float creg = (tid < 256) ? g_c[b*NH + tid] : 0.f;
  float hl = 0.f;
  __syncthreads();

  for (int t = 0; t < NT; ++t){
    // ===== S0: q-projection partials (0-255) + logits partials for h_{t-1} (256-511) =====
    if (tid < 256){
      const int c2 = (tid & 127)*2, kh = tid >> 7;       // k-half
      float a0 = 0.f, a1 = 0.f;
      const unsigned short* wp = WqT + (size_t)(kh*128)*256 + c2;
      #pragma unroll 8
      for (int k = 0; k < 128; ++k){
        unsigned u = *(const unsigned*)(wp + (size_t)k*256);
        float a = sH[kh*128 + k];
        a0 += a*lo_bf(u); a1 += a*hi_bf(u);
      }
      sTMP[kh*256 + c2] = a0; sTMP[kh*256 + c2 + 1] = a1;
    } else {
      const int lt = tid - 256;
      const int c2 = (lt & 63)*2, kq = lt >> 6;          // k-quarter
      float a0 = 0.f, a1 = 0.f;
      const unsigned short* wp = WfcT + (size_t)(kq*64)*128 + c2;
      #pragma unroll 8
      for (int k = 0; k < 64; ++k){
        unsigned u = *(const unsigned*)(wp + (size_t)k*128);
        float a = sH[kq*64 + k];
        a0 += a*lo_bf(u); a1 += a*hi_bf(u);
      }
      sTMP[512 + kq*128 + c2] = a0; sTMP[512 + kq*128 + c2 + 1] = a1;
    }
    __syncthreads();
    // ===== S1: combine q; write logits[t-1]; gather emb_t =====
    if (tid < 256){
      sQ[tid] = sTMP[tid] + sTMP[256 + tid];
    } else if (tid < 384){
      if (t > 0){
        int vc = tid - 256;   // 0..127
        float lv = sBfc[vc] + sTMP[512+vc] + sTMP[640+vc] + sTMP[768+vc] + sTMP[896+vc];
        logits[((size_t)b*NT + (t-1))*NV + vc] = lv;
      }
    } else if (tid >= 448){
      int l = tid - 448;      // 0..63
      sXe[l] = emb[(int)sXi[t]*NE + l];
    }
    __syncthreads();
    // ===== S2: energy partials — keys_t[b][k][t] coalesced along T =====
    {
      const int kh = tid >> 7;        // k-quarter (64 k each), wave-uniform
      const int sp = tid & 127;       // 4 positions: sp*4..+3
      const unsigned short* ktp = keys_t + ((size_t)b*NH + kh*64)*NT + sp*4;
      float e0=0.f, e1=0.f, e2=0.f, e3=0.f;
      #pragma unroll 8
      for (int kk = 0; kk < 64; ++kk){
        uint2 u = *(const uint2*)(ktp + (size_t)kk*NT);
        float qk = sQ[kh*64 + kk], vk = sV[kh*64 + kk];
        e0 += vk*ftanh(qk + lo_bf(u.x));
        e1 += vk*ftanh(qk + hi_bf(u.x));
        e2 += vk*ftanh(qk + lo_bf(u.y));
        e3 += vk*ftanh(qk + hi_bf(u.y));
      }
      *(float4*)(sTMP + kh*512 + sp*4) = make_float4(e0,e1,e2,e3);
    }
    __syncthreads();
    // ===== S3: combine energies, mask, exp, per-wave denominator partials =====
    {
      float e = sTMP[tid] + sTMP[512+tid] + sTMP[1024+tid] + sTMP[1536+tid];
      float w = (sXi[tid] == 0) ? 0.f : __expf(e);
      sWp[tid] = w;
      float s = w;
      #pragma unroll
      for (int off = 32; off > 0; off >>= 1) s += __shfl_down(s, off, 64);
      if ((tid & 63) == 0) sRed[tid >> 6] = s;
    }
    __syncthreads();
    // ===== S4: context partials — enc_out[b][t][h] coalesced along H =====
    {
      const int sc = tid >> 5;        // s-chunk (32 positions)
      const int kc = tid & 31;        // 8 cols: kc*8..+7
      const unsigned short* ep = enc_out + ((size_t)b*NT + sc*32)*NH + kc*8;
      float a0=0.f,a1=0.f,a2=0.f,a3=0.f,a4=0.f,a5=0.f,a6=0.f,a7=0.f;
      #pragma unroll 4
      for (int ss = 0; ss < 32; ++ss){
        float w = sWp[sc*32 + ss];
        uint4 u = *(const uint4*)(ep + (size_t)ss*NH);
        a0 += w*lo_bf(u.x); a1 += w*hi_bf(u.x);
        a2 += w*lo_bf(u.y); a3 += w*hi_bf(u.y);
        a4 += w*lo_bf(u.z); a5 += w*hi_bf(u.z);
        a6 += w*lo_bf(u.w); a7 += w*hi_bf(u.w);
      }
      *(float4*)(sTMP + sc*256 + kc*8)     = make_float4(a0,a1,a2,a3);
      *(float4*)(sTMP + sc*256 + kc*8 + 4) = make_float4(a4,a5,a6,a7);
    }
    __syncthreads();
    // ===== S5: combine context =====
    if (tid < 256){
      float den = sRed[0]+sRed[1]+sRed[2]+sRed[3]+sRed[4]+sRed[5]+sRed[6]+sRed[7];
      float rden = (den > 0.f) ? (1.f/den) : 0.f;
      float cs = 0.f;
      #pragma unroll
      for (int p = 0; p < 16; ++p) cs += sTMP[p*256 + tid];
      sCtx[tid] = cs * rden;
    }
    __syncthreads();
    // ===== S6: gates — stream k-major weights, lanes along gate axis (coalesced) =====
    {
      const int g2 = tid*2;
      float a0 = sBiasD[g2], a1 = sBiasD[g2+1];
      const unsigned short* wi = WihT + g2;
      #pragma unroll 8
      for (int k = 0; k < NE; ++k){
        unsigned u = *(const unsigned*)(wi + (size_t)k*1024);
        float a = sXe[k];
        a0 += a*lo_bf(u); a1 += a*hi_bf(u);
      }
      const unsigned short* wc = WihT + (size_t)NE*1024 + g2;
      #pragma unroll 8
      for (int k = 0; k < NH; ++k){
        unsigned u = *(const unsigned*)(wc + (size_t)k*1024);
        float a = sCtx[k];
        a0 += a*lo_bf(u); a1 += a*hi_bf(u);
      }
      const unsigned short* wh = WhhT + g2;
      #pragma unroll 8
      for (int k = 0; k < NH; ++k){
        unsigned u = *(const unsigned*)(wh + (size_t)k*1024);
        float a = sH[k];
        a0 += a*lo_bf(u); a1 += a*hi_bf(u);
      }
      sG[g2] = a0; sG[g2+1] = a1;
    }
    __syncthreads();
    // ===== S7: cell update =====
    if (tid < 256){
      float gi = sigm (sG[tid]);
      float gf = sigm (sG[256 + tid]);
      float gg = ftanh(sG[512 + tid]);
      float go = sigm (sG[768 + tid]);
      float cn = gf*creg + gi*gg;
      float hn = go*ftanh(cn);
      creg = cn; hl = hn;
      sH[tid] = hn;
    }
    __syncthreads();
  }

  // ===== final logits (h_511) + h_f, c_f =====
  if (tid >= 256){
    const int lt = tid - 256;
    const int c2 = (lt & 63)*2, kq = lt >> 6;
    float a0 = 0.f, a1 = 0.f;
    const unsigned short* wp = WfcT + (size_t)(kq*64)*128 + c2;
    #pragma unroll 8
    for (int k = 0; k < 64; ++k){
      unsigned u = *(const unsigned*)(wp + (size_t)k*128);
      float a = sH[kq*64 + k];
      a0 += a*lo_bf(u); a1 += a*hi_bf(u);
    }
    sTMP[512 + kq*128 + c2] = a0; sTMP[512 + kq*128 + c2 + 1] = a1;
  }
  __syncthreads();
  if (tid >= 256 && tid < 384){
    int vc = tid - 256;
    float lv = sBfc[vc] + sTMP[512+vc] + sTMP[640+vc] + sTMP[768+vc] + sTMP[896+vc];
    logits[((size_t)b*NT + (NT-1))*NV + vc] = lv;
  }
  if (tid < 256){
    out_h[b*NH + tid] = hl;
    out_c[b*NH + tid] = creg;
  }
}

// ---------------- launcher ----------------
extern "C" void kernel_launch(void* const* d_in, const int* in_sizes, int n_in,
                              void* d_out, int out_size, void* d_ws, size_t ws_size,
                              hipStream_t stream)
{
  (void)in_sizes; (void)n_in; (void)out_size; (void)ws_size;
  const int*   x    = (const int*)  d_in[0];
  const float* emb  = (const float*)d_in[1];
  const float* Wihe = (const float*)d_in[2];
  const float* Whhe = (const float*)d_in[3];
  const float* bihe = (const float*)d_in[4];
  const float* bhhe = (const float*)d_in[5];
  const float* Wq   = (const float*)d_in[6];
  const float* Wk   = (const float*)d_in[7];
  const float* vv   = (const float*)d_in[8];
  const float* Wihd = (const float*)d_in[9];
  const float* Whhd = (const float*)d_in[10];
  const float* bihd = (const float*)d_in[11];
  const float* bhhd = (const float*)d_in[12];
  const float* Wfc  = (const float*)d_in[13];
  const float* bfc  = (const float*)d_in[14];

  char* ws = (char*)d_ws;
  unsigned* ctrs = (unsigned*)ws;                                  // 8 KB
  unsigned short* enc   = (unsigned short*)(ws + 8192);            // 64 MB bf16 [B][T][H]
  unsigned short* keyst = (unsigned short*)(ws + 8192 + 67108864); // 64 MB bf16 [B][H][T]
  float* g_h  = (float*)(ws + 8192 + 2*67108864);                  // 2 * B*H f32
  float* g_c  = g_h + 2*NB*NH;                                     // B*H f32
  unsigned short* WqT  = (unsigned short*)(g_c + NB*NH);           // 256*256 bf16
  unsigned short* WfcT = WqT  + 256*256;                           // 256*128 bf16
  unsigned short* WihT = WfcT + 256*128;                           // 320*1024 bf16
  unsigned short* WhhT = WihT + 320*1024;                          // 256*1024 bf16

  float* out_logits = (float*)d_out;
  float* out_h = out_logits + (size_t)NB*NT*NV;
  float* out_c = out_h + NB*NH;

  hipMemsetAsync(ctrs, 0, 8192, stream);

  const size_t smem_enc = (size_t)(64*64 + 256*64 + 16*260 + 64 + 16*256 + 16*64 + 64*17)*4 + 16*512;

  prep_kernel<<<dim3(1088), dim3(256), 0, stream>>>(Wq, Wfc, Wihd, Whhd, WqT, WfcT, WihT, WhhT);
  enc_kernel<<<dim3(256), dim3(256), smem_enc, stream>>>(
      x, emb, Wihe, Whhe, bihe, bhhe, Wk, enc, keyst, g_h, g_c, ctrs);
  dec_kernel<<<dim3(256), dim3(512), 0, stream>>>(
      x, emb, WqT, vv, WihT, WhhT, bihd, bhhd, WfcT, bfc,
      enc, keyst, g_h, g_c, out_logits, out_h, out_c);
}

// Round 5
// 55119.177 us; speedup vs baseline: 5.9850x; 1.1751x over previous
//
#include <hip/hip_runtime.h>
#include <hip/hip_bf16.h>
#include <stdint.h>

#define NB 256   // batch
#define NT 512   // time
#define NV 128   // vocab
#define NE 64    // embed
#define NH 256   // hidden

// ---------------- helpers ----------------
__device__ __forceinline__ float lo_bf(unsigned u){ return __uint_as_float(u << 16); }
__device__ __forceinline__ float hi_bf(unsigned u){ return __uint_as_float(u & 0xffff0000u); }
__device__ __forceinline__ unsigned short f2us(float f){
  unsigned u = __float_as_uint(f);
  unsigned r = u + 0x7fffu + ((u >> 16) & 1u);
  return (unsigned short)(r >> 16);
}
__device__ __forceinline__ float sigm(float x){
  return __builtin_amdgcn_rcpf(1.f + __expf(-x));
}
__device__ __forceinline__ float ftanh(float xx){
  float a = fabsf(xx);
  a = fminf(a, 9.f);
  float e = __expf(2.f * a);
  float r = __builtin_amdgcn_rcpf(e + 1.f);
  float t = (e - 1.f) * r;
  return copysignf(t, xx);
}

// 16-workgroup group barrier (monotonic counter, device scope) — ENCODER ONLY
__device__ __forceinline__ void groupbar(unsigned* c, unsigned target){
  __threadfence();
  __syncthreads();
  if (threadIdx.x == 0){
    __hip_atomic_fetch_add(c, 1u, __ATOMIC_RELEASE, __HIP_MEMORY_SCOPE_AGENT);
    while (__hip_atomic_load(c, __ATOMIC_ACQUIRE, __HIP_MEMORY_SCOPE_AGENT) < target)
      __builtin_amdgcn_s_sleep(2);
  }
  __syncthreads();
  __threadfence();
}

// ---------------- prep: transpose decoder weights to k-major bf16 ----------------
__global__ __launch_bounds__(256, 1)
void prep_kernel(const float* __restrict__ Wq, const float* __restrict__ Wfc,
                 const float* __restrict__ Wih, const float* __restrict__ Whh,
                 unsigned short* __restrict__ WqT, unsigned short* __restrict__ WfcT,
                 unsigned short* __restrict__ WihT, unsigned short* __restrict__ WhhT)
{
  const int blk = blockIdx.x, tid = threadIdx.x;
  if (blk < 256){                       // WqT[k][c], k = blk
    WqT[blk*256 + tid] = f2us(Wq[tid*256 + blk]);
  } else if (blk < 512){                // WfcT[k][v], k = blk-256
    int k = blk - 256;
    if (tid < 128) WfcT[k*128 + tid] = f2us(Wfc[tid*256 + k]);
  } else if (blk < 832){                // WihT[k][g], k = blk-512 (0..319)
    int k = blk - 512;
    #pragma unroll
    for (int j = 0; j < 4; ++j){
      int g = tid + j*256;
      WihT[k*1024 + g] = f2us(Wih[g*320 + k]);
    }
  } else {                              // WhhT[k][g], k = blk-832 (0..255)
    int k = blk - 832;
    #pragma unroll
    for (int j = 0; j < 4; ++j){
      int g = tid + j*256;
      WhhT[k*1024 + g] = f2us(Whh[g*256 + k]);
    }
  }
}

// ---------------- key transpose: keys_n[B][T][H] -> keys_t[B][H][T] ----------------
// grid: B * (NT/64) * (NH/64) = 256*8*4 = 8192 blocks, 256 threads
__global__ __launch_bounds__(256, 1)
void tr_kernel(const unsigned short* __restrict__ keys_n, unsigned short* __restrict__ keys_t)
{
  __shared__ unsigned short tile[64][68];   // padded
  const int blk = blockIdx.x, tid = threadIdx.x;
  const int b  = blk >> 5;
  const int tt = (blk >> 2) & 7;    // t-tile
  const int hh = blk & 3;           // h-tile
  const int t0 = tt*64, h0 = hh*64;

  // load 64x64 tile, coalesced along H (uint2 = 4 bf16)
  #pragma unroll
  for (int i = 0; i < 4; ++i){
    int idx = tid + i*256;              // 0..1023 uint2 slots
    int t = idx >> 4, h4 = (idx & 15)*4;
    uint2 u = *(const uint2*)(keys_n + ((size_t)b*NT + t0 + t)*NH + h0 + h4);
    *(uint2*)&tile[t][h4] = u;
  }
  __syncthreads();
  // write coalesced along T
  #pragma unroll
  for (int i = 0; i < 4; ++i){
    int idx = tid + i*256;
    int h = idx >> 4, t4 = (idx & 15)*4;
    unsigned short a = tile[t4+0][h], bb = tile[t4+1][h], cc = tile[t4+2][h], dd = tile[t4+3][h];
    uint2 u; u.x = (unsigned)a | ((unsigned)bb << 16); u.y = (unsigned)cc | ((unsigned)dd << 16);
    *(uint2*)(keys_t + ((size_t)b*NH + h0 + h)*NT + t0 + t4) = u;
  }
}

// ---------------- encoder (persistent, 512 steps, fuses keys_proj) ----------------
// keys written COALESCED [B][T][H]; transposed later by tr_kernel
__global__ __launch_bounds__(256, 1)
void enc_kernel(const int* __restrict__ x, const float* __restrict__ emb,
                const float* __restrict__ Wih, const float* __restrict__ Whh,
                const float* __restrict__ bih, const float* __restrict__ bhh,
                const float* __restrict__ Wk,
                unsigned short* __restrict__ enc_out, unsigned short* __restrict__ keys_n,
                float* __restrict__ g_h, float* __restrict__ g_c,
                unsigned* __restrict__ ctrs)
{
  const int tid = threadIdx.x;
  const int blk = blockIdx.x;
  const int gb = blk >> 4, gc = blk & 15;
  const int r0 = gb * 16, c0 = gc * 16;

  extern __shared__ char smem[];
  float* sWi   = (float*)smem;                 // [64][64]
  float* sWh   = sWi  + 64*64;                 // [256][64]
  float* sWk   = sWh  + 256*64;                // [16][260]
  float* sBias = sWk  + 16*260;                // [64]
  float* sH    = sBias + 64;                   // [16][256]
  float* sXe   = sH   + 16*256;                // [16][64]
  float* sG    = sXe  + 16*64;                 // [64][17]
  uint8_t* sXi = (uint8_t*)(sG + 64*17);       // [16][512]

  for (int i = tid; i < 64*64; i += 256){
    int cj = i & 63, k = i >> 6;
    int grow = ((cj >> 4) * NH) + c0 + (cj & 15);
    sWi[k*64 + cj] = Wih[grow*NE + k];
  }
  for (int i = tid; i < 256*64; i += 256){
    int cj = i & 63, k = i >> 6;
    int grow = ((cj >> 4) * NH) + c0 + (cj & 15);
    sWh[k*64 + cj] = Whh[grow*NH + k];
  }
  if (tid < 64){
    int grow = ((tid >> 4) * NH) + c0 + (tid & 15);
    sBias[tid] = bih[grow] + bhh[grow];
  }
  for (int i = tid; i < 16*256; i += 256){
    int qc = i >> 8, k = i & 255;
    sWk[qc*260 + k] = Wk[(c0 + qc)*NH + k];
  }
  for (int i = tid; i < 16*512; i += 256){
    int rr = i >> 9;
    sXi[i] = (uint8_t)x[(r0 + rr)*NT + (i & 511)];
  }
  for (int i = tid; i < 16*256; i += 256) sH[i] = 0.f;
  __syncthreads();

  const int r  = tid >> 4;
  const int cq = tid & 15;
  float creg = 0.f;
  unsigned* ctr = ctrs + gb*16;

  for (int t = 0; t < NT; ++t){
    if (t > 0){
      float kv = 0.f;
      const float4* hv = (const float4*)(sH + r*256);
      const float4* wv = (const float4*)(sWk + cq*260);
      #pragma unroll 8
      for (int k4 = 0; k4 < 64; ++k4){
        float4 a = hv[k4], w = wv[k4];
        kv += a.x*w.x + a.y*w.y + a.z*w.z + a.w*w.w;
      }
      keys_n[((size_t)(r0 + r)*NT + (t-1))*NH + c0 + cq] = f2us(kv);
    }
    {
      int idx = sXi[r*512 + t];
      float4 ev = *(const float4*)(emb + idx*NE + cq*4);
      *(float4*)(sXe + r*64 + cq*4) = ev;
    }
    __syncthreads();
    {
      float4 acc = *(float4*)&sBias[cq*4];
      #pragma unroll 8
      for (int k = 0; k < NE; ++k){
        float a = sXe[r*64 + k];
        float4 w = *(const float4*)(sWi + k*64 + cq*4);
        acc.x += a*w.x; acc.y += a*w.y; acc.z += a*w.z; acc.w += a*w.w;
      }
      #pragma unroll 8
      for (int k = 0; k < NH; ++k){
        float a = sH[r*256 + k];
        float4 w = *(const float4*)(sWh + k*64 + cq*4);
        acc.x += a*w.x; acc.y += a*w.y; acc.z += a*w.z; acc.w += a*w.w;
      }
      sG[(cq*4 + 0)*17 + r] = acc.x;
      sG[(cq*4 + 1)*17 + r] = acc.y;
      sG[(cq*4 + 2)*17 + r] = acc.z;
      sG[(cq*4 + 3)*17 + r] = acc.w;
    }
    __syncthreads();
    {
      float gi = sigm (sG[( 0 + cq)*17 + r]);
      float gf = sigm (sG[(16 + cq)*17 + r]);
      float gg = ftanh(sG[(32 + cq)*17 + r]);
      float go = sigm (sG[(48 + cq)*17 + r]);
      float cn = gf*creg + gi*gg;
      float hn = go*ftanh(cn);
      creg = cn;
      g_h[((t+1)&1)*NB*NH + (r0+r)*NH + c0 + cq] = hn;
      enc_out[((size_t)(r0+r)*NT + t)*NH + c0 + cq] = f2us(hn);
    }
    groupbar(ctr, (unsigned)(16*(t+1)));
    {
      const float4* src = (const float4*)(g_h + ((t+1)&1)*NB*NH + r0*NH);
      float4* dst = (float4*)sH;
      #pragma unroll 4
      for (int i = tid; i < 1024; i += 256) dst[i] = src[i];
    }
    __syncthreads();
  }
  {
    float kv = 0.f;
    const float4* hv = (const float4*)(sH + r*256);
    const float4* wv = (const float4*)(sWk + cq*260);
    #pragma unroll 8
    for (int k4 = 0; k4 < 64; ++k4){
      float4 a = hv[k4], w = wv[k4];
      kv += a.x*w.x + a.y*w.y + a.z*w.z + a.w*w.w;
    }
    keys_n[((size_t)(r0 + r)*NT + (NT-1))*NH + c0 + cq] = f2us(kv);
  }
  g_c[(r0 + r)*NH + c0 + cq] = creg;
}

// ---------------- decoder: ONE batch row per WG, 1024 threads, WG-local, no global sync ----------------
__global__ __launch_bounds__(1024, 1)
void dec_kernel(const int* __restrict__ x, const float* __restrict__ emb,
                const unsigned short* __restrict__ WqT, const float* __restrict__ vvec,
                const unsigned short* __restrict__ WihT, const unsigned short* __restrict__ WhhT,
                const float* __restrict__ bih, const float* __restrict__ bhh,
                const unsigned short* __restrict__ WfcT, const float* __restrict__ bfc,
                const unsigned short* __restrict__ enc_out, const unsigned short* __restrict__ keys_t,
                const float* __restrict__ g_h, const float* __restrict__ g_c,
                float* __restrict__ logits, float* __restrict__ out_h, float* __restrict__ out_c)
{
  const int tid = threadIdx.x;
  const int b   = blockIdx.x;           // this WG's batch row

  __shared__ float sTMP[4096];          // 16KB scratch (partials)
  __shared__ float sWp[512];            // softmax numerators
  __shared__ float sRed[8];
  __shared__ float sQ[256];
  __shared__ float sH[256];
  __shared__ float sCtx[256];
  __shared__ float sXe[64];
  __shared__ float sG[1024];
  __shared__ float sBiasD[1024];
  __shared__ float sBfc[128];
  __shared__ float sV[256];
  __shared__ uint8_t sXi[512];

  // ---- init ----
  sBiasD[tid] = bih[tid] + bhh[tid];
  if (tid < 128) sBfc[tid] = bfc[tid];
  if (tid < 256){ sV[tid] = vvec[tid]; sH[tid] = g_h[b*NH + tid]; }
  if (tid < 512) sXi[tid] = (uint8_t)x[b*NT + tid];
  float creg = (tid < 256) ? g_c[b*NH + tid] : 0.f;
  float hl = 0.f;
  __syncthreads();

  for (int t = 0; t < NT; ++t){
    // ===== S0: q-proj partials (0-511) + logits partials for h_{t-1} (512-1023) =====
    if (tid < 512){
      const int c2 = (tid & 127)*2, kq = tid >> 7;       // 4 k-chunks of 64
      float a0 = 0.f, a1 = 0.f;
      const unsigned short* wp = WqT + (size_t)(kq*64)*256 + c2;
      #pragma unroll 8
      for (int k = 0; k < 64; ++k){
        unsigned u = *(const unsigned*)(wp + (size_t)k*256);
        float a = sH[kq*64 + k];
        a0 += a*lo_bf(u); a1 += a*hi_bf(u);
      }
      sTMP[kq*256 + c2] = a0; sTMP[kq*256 + c2 + 1] = a1;
    } else {
      const int lt = tid - 512;
      const int v2 = (lt & 63)*2, k8 = lt >> 6;          // 8 k-chunks of 32
      float a0 = 0.f, a1 = 0.f;
      const unsigned short* wp = WfcT + (size_t)(k8*32)*128 + v2;
      #pragma unroll 8
      for (int k = 0; k < 32; ++k){
        unsigned u = *(const unsigned*)(wp + (size_t)k*128);
        float a = sH[k8*32 + k];
        a0 += a*lo_bf(u); a1 += a*hi_bf(u);
      }
      sTMP[1024 + k8*128 + v2] = a0; sTMP[1024 + k8*128 + v2 + 1] = a1;
    }
    __syncthreads();
    // ===== S1: combine q; write logits[t-1]; gather emb_t =====
    if (tid < 256){
      sQ[tid] = sTMP[tid] + sTMP[256 + tid] + sTMP[512 + tid] + sTMP[768 + tid];
    } else if (tid >= 512 && tid < 640){
      if (t > 0){
        int vc = tid - 512;
        float lv = sBfc[vc];
        #pragma unroll
        for (int p = 0; p < 8; ++p) lv += sTMP[1024 + p*128 + vc];
        logits[((size_t)b*NT + (t-1))*NV + vc] = lv;
      }
    } else if (tid >= 448 && tid < 512){
      int l = tid - 448;
      sXe[l] = emb[(int)sXi[t]*NE + l];
    }
    __syncthreads();
    // ===== S2: energy partials — keys_t[b][k][t] coalesced along T =====
    {
      const int kh = tid >> 7;        // 8 k-chunks of 32
      const int sp = tid & 127;       // 4 positions each
      const unsigned short* ktp = keys_t + ((size_t)b*NH + kh*32)*NT + sp*4;
      float e0=0.f, e1=0.f, e2=0.f, e3=0.f;
      #pragma unroll 8
      for (int kk = 0; kk < 32; ++kk){
        uint2 u = *(const uint2*)(ktp + (size_t)kk*NT);
        float qk = sQ[kh*32 + kk], vk = sV[kh*32 + kk];
        e0 += vk*ftanh(qk + lo_bf(u.x));
        e1 += vk*ftanh(qk + hi_bf(u.x));
        e2 += vk*ftanh(qk + lo_bf(u.y));
        e3 += vk*ftanh(qk + hi_bf(u.y));
      }
      *(float4*)(sTMP + kh*512 + sp*4) = make_float4(e0,e1,e2,e3);
    }
    __syncthreads();
    // ===== S3: combine energies, mask, exp, per-wave denom partials =====
    if (tid < 512){
      float e = sTMP[tid]      + sTMP[512+tid]  + sTMP[1024+tid] + sTMP[1536+tid]
              + sTMP[2048+tid] + sTMP[2560+tid] + sTMP[3072+tid] + sTMP[3584+tid];
      float w = (sXi[tid] == 0) ? 0.f : __expf(e);
      sWp[tid] = w;
      float s = w;
      #pragma unroll
      for (int off = 32; off > 0; off >>= 1) s += __shfl_down(s, off, 64);
      if ((tid & 63) == 0) sRed[tid >> 6] = s;
    }
    __syncthreads();
    // ===== S4: context partials — enc_out[b][t][h] coalesced along H =====
    {
      const int sc = tid >> 6;        // 16 s-chunks of 32
      const int kc = tid & 63;        // 4 cols each
      const unsigned short* ep = enc_out + ((size_t)b*NT + sc*32)*NH + kc*4;
      float a0=0.f, a1=0.f, a2=0.f, a3=0.f;
      #pragma unroll 8
      for (int ss = 0; ss < 32; ++ss){
        float w = sWp[sc*32 + ss];
        uint2 u = *(const uint2*)(ep + (size_t)ss*NH);
        a0 += w*lo_bf(u.x); a1 += w*hi_bf(u.x);
        a2 += w*lo_bf(u.y); a3 += w*hi_bf(u.y);
      }
      *(float4*)(sTMP + sc*256 + kc*4) = make_float4(a0,a1,a2,a3);
    }
    __syncthreads();
    // ===== S5: combine context =====
    if (tid < 256){
      float den = sRed[0]+sRed[1]+sRed[2]+sRed[3]+sRed[4]+sRed[5]+sRed[6]+sRed[7];
      float rden = (den > 0.f) ? (1.f/den) : 0.f;
      float cs = 0.f;
      #pragma unroll
      for (int p = 0; p < 16; ++p) cs += sTMP[p*256 + tid];
      sCtx[tid] = cs * rden;
    }
    __syncthreads();
    // ===== S6: gate partials — 2 k-segments x 512 gate-pairs, coalesced along G =====
    {
      const int kseg = tid >> 9;            // 0 or 1 (wave-uniform)
      const int g2 = (tid & 511)*2;
      float a0 = 0.f, a1 = 0.f;
      if (kseg == 0){
        // k = 0..287: xe(64) + ctx(0..223), all WihT
        const unsigned short* wi = WihT + g2;
        #pragma unroll 8
        for (int k = 0; k < 64; ++k){
          unsigned u = *(const unsigned*)(wi + (size_t)k*1024);
          float a = sXe[k];
          a0 += a*lo_bf(u); a1 += a*hi_bf(u);
        }
        const unsigned short* wc = WihT + (size_t)64*1024 + g2;
        #pragma unroll 8
        for (int k = 0; k < 224; ++k){
          unsigned u = *(const unsigned*)(wc + (size_t)k*1024);
          float a = sCtx[k];
          a0 += a*lo_bf(u); a1 += a*hi_bf(u);
        }
      } else {
        // k = 288..575: ctx(224..255) + h(0..255)
        const unsigned short* wc = WihT + (size_t)(64+224)*1024 + g2;
        #pragma unroll 8
        for (int k = 0; k < 32; ++k){
          unsigned u = *(const unsigned*)(wc + (size_t)k*1024);
          float a = sCtx[224 + k];
          a0 += a*lo_bf(u); a1 += a*hi_bf(u);
        }
        const unsigned short* wh = WhhT + g2;
        #pragma unroll 8
        for (int k = 0; k < 256; ++k){
          unsigned u = *(const unsigned*)(wh + (size_t)k*1024);
          float a = sH[k];
          a0 += a*lo_bf(u); a1 += a*hi_bf(u);
        }
      }
      sTMP[kseg*1024 + g2] = a0;
      sTMP[kseg*1024 + g2 + 1] = a1;
    }
    __syncthreads();
    // ===== S6b: combine gates =====
    if (tid < 512){
      const int g2 = tid*2;
      sG[g2]   = sBiasD[g2]   + sTMP[g2]   + sTMP[1024 + g2];
      sG[g2+1] = sBiasD[g2+1] + sTMP[g2+1] + sTMP[1024 + g2 + 1];
    }
    __syncthreads();
    // ===== S7: cell update =====
    if (tid < 256){
      float gi = sigm (sG[tid]);
      float gf = sigm (sG[256 + tid]);
      float gg = ftanh(sG[512 + tid]);
      float go = sigm (sG[768 + tid]);
      float cn = gf*creg + gi*gg;
      float hn = go*ftanh(cn);
      creg = cn; hl = hn;
      sH[tid] = hn;
    }
    __syncthreads();
  }

  // ===== final logits (h_511) + h_f, c_f =====
  if (tid >= 512){
    const int lt = tid - 512;
    const int v2 = (lt & 63)*2, k8 = lt >> 6;
    float a0 = 0.f, a1 = 0.f;
    const unsigned short* wp = WfcT + (size_t)(k8*32)*128 + v2;
    #pragma unroll 8
    for (int k = 0; k < 32; ++k){
      unsigned u = *(const unsigned*)(wp + (size_t)k*128);
      float a = sH[k8*32 + k];
      a0 += a*lo_bf(u); a1 += a*hi_bf(u);
    }
    sTMP[1024 + k8*128 + v2] = a0; sTMP[1024 + k8*128 + v2 + 1] = a1;
  }
  __syncthreads();
  if (tid >= 512 && tid < 640){
    int vc = tid - 512;
    float lv = sBfc[vc];
    #pragma unroll
    for (int p = 0; p < 8; ++p) lv += sTMP[1024 + p*128 + vc];
    logits[((size_t)b*NT + (NT-1))*NV + vc] = lv;
  }
  if (tid < 256){
    out_h[b*NH + tid] = hl;
    out_c[b*NH + tid] = creg;
  }
}

// ---------------- launcher ----------------
extern "C" void kernel_launch(void* const* d_in, const int* in_sizes, int n_in,
                              void* d_out, int out_size, void* d_ws, size_t ws_size,
                              hipStream_t stream)
{
  (void)in_sizes; (void)n_in; (void)out_size; (void)ws_size;
  const int*   x    = (const int*)  d_in[0];
  const float* emb  = (const float*)d_in[1];
  const float* Wihe = (const float*)d_in[2];
  const float* Whhe = (const float*)d_in[3];
  const float* bihe = (const float*)d_in[4];
  const float* bhhe = (const float*)d_in[5];
  const float* Wq   = (const float*)d_in[6];
  const float* Wk   = (const float*)d_in[7];
  const float* vv   = (const float*)d_in[8];
  const float* Wihd = (const float*)d_in[9];
  const float* Whhd = (const float*)d_in[10];
  const float* bihd = (const float*)d_in[11];
  const float* bhhd = (const float*)d_in[12];
  const float* Wfc  = (const float*)d_in[13];
  const float* bfc  = (const float*)d_in[14];

  char* ws = (char*)d_ws;
  unsigned* ctrs = (unsigned*)ws;                                  // 8 KB
  unsigned short* enc   = (unsigned short*)(ws + 8192);            // 64 MB bf16 [B][T][H]
  unsigned short* keysn = (unsigned short*)(ws + 8192 + 67108864); // 64 MB bf16 [B][T][H]
  unsigned short* keyst = (unsigned short*)(ws + 8192 + 2*67108864); // 64 MB bf16 [B][H][T]
  float* g_h  = (float*)(ws + 8192 + (size_t)3*67108864);          // 2 * B*H f32
  float* g_c  = g_h + 2*NB*NH;                                     // B*H f32
  unsigned short* WqT  = (unsigned short*)(g_c + NB*NH);           // 256*256 bf16
  unsigned short* WfcT = WqT  + 256*256;                           // 256*128 bf16
  unsigned short* WihT = WfcT + 256*128;                           // 320*1024 bf16
  unsigned short* WhhT = WihT + 320*1024;                          // 256*1024 bf16

  float* out_logits = (float*)d_out;
  float* out_h = out_logits + (size_t)NB*NT*NV;
  float* out_c = out_h + NB*NH;

  hipMemsetAsync(ctrs, 0, 8192, stream);

  const size_t smem_enc = (size_t)(64*64 + 256*64 + 16*260 + 64 + 16*256 + 16*64 + 64*17)*4 + 16*512;

  prep_kernel<<<dim3(1088), dim3(256), 0, stream>>>(Wq, Wfc, Wihd, Whhd, WqT, WfcT, WihT, WhhT);
  enc_kernel<<<dim3(256), dim3(256), smem_enc, stream>>>(
      x, emb, Wihe, Whhe, bihe, bhhe, Wk, enc, keysn, g_h, g_c, ctrs);
  tr_kernel<<<dim3(8192), dim3(256), 0, stream>>>(keysn, keyst);
  dec_kernel<<<dim3(256), dim3(1024), 0, stream>>>(
      x, emb, WqT, vv, WihT, WhhT, bihd, bhhd, WfcT, bfc,
      enc, keyst, g_h, g_c, out_logits, out_h, out_c);
}

// Round 6
// 34799.713 us; speedup vs baseline: 9.4797x; 1.5839x over previous
//
#include <hip/hip_runtime.h>
#include <hip/hip_bf16.h>
#include <stdint.h>

#define NB 256   // batch
#define NT 512   // time
#define NV 128   // vocab
#define NE 64    // embed
#define NH 256   // hidden

// ---------------- helpers ----------------
__device__ __forceinline__ float lo_bf(unsigned u){ return __uint_as_float(u << 16); }
__device__ __forceinline__ float hi_bf(unsigned u){ return __uint_as_float(u & 0xffff0000u); }
__device__ __forceinline__ unsigned short f2us(float f){
  unsigned u = __float_as_uint(f);
  unsigned r = u + 0x7fffu + ((u >> 16) & 1u);
  return (unsigned short)(r >> 16);
}
__device__ __forceinline__ float sigm(float x){
  return __builtin_amdgcn_rcpf(1.f + __expf(-x));
}
__device__ __forceinline__ float ftanh(float xx){
  float a = fabsf(xx);
  a = fminf(a, 9.f);
  float e = __expf(2.f * a);
  float r = __builtin_amdgcn_rcpf(e + 1.f);
  float t = (e - 1.f) * r;
  return copysignf(t, xx);
}

// ---------------- prep: transpose weights ----------------
// dec weights -> k-major bf16 ; enc weights -> k-major f32
__global__ __launch_bounds__(256, 1)
void prep_kernel(const float* __restrict__ Wq, const float* __restrict__ Wfc,
                 const float* __restrict__ Wih, const float* __restrict__ Whh,
                 const float* __restrict__ Wihe, const float* __restrict__ Whhe,
                 const float* __restrict__ Wk,
                 unsigned short* __restrict__ WqT, unsigned short* __restrict__ WfcT,
                 unsigned short* __restrict__ WihT, unsigned short* __restrict__ WhhT,
                 float* __restrict__ WiheT, float* __restrict__ WhheT,
                 float* __restrict__ WkT)
{
  const int blk = blockIdx.x, tid = threadIdx.x;
  if (blk < 256){                       // WqT[k][c], k = blk
    WqT[blk*256 + tid] = f2us(Wq[tid*256 + blk]);
  } else if (blk < 512){                // WfcT[k][v], k = blk-256
    int k = blk - 256;
    if (tid < 128) WfcT[k*128 + tid] = f2us(Wfc[tid*256 + k]);
  } else if (blk < 832){                // WihT[k][g], k = blk-512 (0..319)
    int k = blk - 512;
    #pragma unroll
    for (int j = 0; j < 4; ++j){
      int g = tid + j*256;
      WihT[k*1024 + g] = f2us(Wih[g*320 + k]);
    }
  } else if (blk < 1088){               // WhhT[k][g], k = blk-832 (0..255)
    int k = blk - 832;
    #pragma unroll
    for (int j = 0; j < 4; ++j){
      int g = tid + j*256;
      WhhT[k*1024 + g] = f2us(Whh[g*256 + k]);
    }
  } else if (blk < 1152){               // WiheT[k][g] f32, k = blk-1088 (0..63)
    int k = blk - 1088;
    #pragma unroll
    for (int j = 0; j < 4; ++j){
      int g = tid + j*256;
      WiheT[k*1024 + g] = Wihe[g*64 + k];
    }
  } else if (blk < 1408){               // WhheT[k][g] f32, k = blk-1152 (0..255)
    int k = blk - 1152;
    #pragma unroll
    for (int j = 0; j < 4; ++j){
      int g = tid + j*256;
      WhheT[k*1024 + g] = Whhe[g*256 + k];
    }
  } else {                              // WkT[k][c] f32, k = blk-1408 (0..255)
    int k = blk - 1408;
    WkT[k*256 + tid] = Wk[tid*256 + k];
  }
}

// ---------------- key transpose: keys_n[B][T][H] -> keys_t[B][H][T] ----------------
__global__ __launch_bounds__(256, 1)
void tr_kernel(const unsigned short* __restrict__ keys_n, unsigned short* __restrict__ keys_t)
{
  __shared__ unsigned short tile[64][68];   // padded
  const int blk = blockIdx.x, tid = threadIdx.x;
  const int b  = blk >> 5;
  const int tt = (blk >> 2) & 7;    // t-tile
  const int hh = blk & 3;           // h-tile
  const int t0 = tt*64, h0 = hh*64;

  #pragma unroll
  for (int i = 0; i < 4; ++i){
    int idx = tid + i*256;              // 0..1023 uint2 slots
    int t = idx >> 4, h4 = (idx & 15)*4;
    uint2 u = *(const uint2*)(keys_n + ((size_t)b*NT + t0 + t)*NH + h0 + h4);
    *(uint2*)&tile[t][h4] = u;
  }
  __syncthreads();
  #pragma unroll
  for (int i = 0; i < 4; ++i){
    int idx = tid + i*256;
    int h = idx >> 4, t4 = (idx & 15)*4;
    unsigned short a = tile[t4+0][h], bb = tile[t4+1][h], cc = tile[t4+2][h], dd = tile[t4+3][h];
    uint2 u; u.x = (unsigned)a | ((unsigned)bb << 16); u.y = (unsigned)cc | ((unsigned)dd << 16);
    *(uint2*)(keys_t + ((size_t)b*NH + h0 + h)*NT + t0 + t4) = u;
  }
}

// ---------------- encoder: 2 batch rows per WG, fully WG-local, NO cross-WG sync ----------------
// 128 WGs x 1024 threads. Weights streamed k-major f32 from L2 (prep-transposed).
__global__ __launch_bounds__(1024, 1)
void enc_kernel(const int* __restrict__ x, const float* __restrict__ emb,
                const float* __restrict__ WiheT, const float* __restrict__ WhheT,
                const float* __restrict__ bih, const float* __restrict__ bhh,
                const float* __restrict__ WkT,
                unsigned short* __restrict__ enc_out, unsigned short* __restrict__ keys_n,
                float* __restrict__ g_h, float* __restrict__ g_c)
{
  const int tid = threadIdx.x;
  const int b0  = blockIdx.x * 2;

  __shared__ float sH[2][256];
  __shared__ float sXe[2][64];
  __shared__ float sG[2][1024];
  __shared__ float sBias[1024];
  __shared__ uint8_t sXi[2][512];

  sBias[tid] = bih[tid] + bhh[tid];
  {
    int r = tid >> 9;
    sXi[r][tid & 511] = (uint8_t)x[(b0 + r)*NT + (tid & 511)];
  }
  if (tid < 512) sH[tid>>8][tid&255] = 0.f;
  float creg = 0.f;
  // prime sXe for t=0
  __syncthreads();
  if (tid < 32){
    int r = tid >> 4, q = tid & 15;
    int idx = sXi[r][0];
    *(float4*)&sXe[r][q*4] = *(const float4*)(emb + idx*NE + q*4);
  }
  __syncthreads();

  for (int t = 0; t < NT; ++t){
    // ===== phase B: gates (tid 0-511: 2 gates x 2 rows) | keys[t-1] (tid 512-1023) =====
    if (tid < 512){
      const int g2 = tid*2;
      float a00 = sBias[g2], a01 = sBias[g2+1];   // row0
      float a10 = a00, a11 = a01;                  // row1
      const float2* wi = (const float2*)(WiheT + g2);
      #pragma unroll 8
      for (int k = 0; k < NE; ++k){
        float2 w = wi[(size_t)k*512];
        float x0 = sXe[0][k], x1 = sXe[1][k];
        a00 += x0*w.x; a01 += x0*w.y;
        a10 += x1*w.x; a11 += x1*w.y;
      }
      const float2* wh = (const float2*)(WhheT + g2);
      #pragma unroll 8
      for (int k = 0; k < NH; ++k){
        float2 w = wh[(size_t)k*512];
        float h0 = sH[0][k], h1 = sH[1][k];
        a00 += h0*w.x; a01 += h0*w.y;
        a10 += h1*w.x; a11 += h1*w.y;
      }
      sG[0][g2] = a00; sG[0][g2+1] = a01;
      sG[1][g2] = a10; sG[1][g2+1] = a11;
    } else if (t > 0){
      const int lt = tid - 512;
      const int r = lt >> 8, cc = lt & 255;
      float kv = 0.f;
      const float* wk = WkT + cc;
      #pragma unroll 8
      for (int k = 0; k < NH; ++k) kv += sH[r][k] * wk[(size_t)k*256];
      keys_n[((size_t)(b0 + r)*NT + (t-1))*NH + cc] = f2us(kv);
    }
    __syncthreads();
    // ===== phase C: cell update (tid 0-511) | emb gather for t+1 (tid 512-543) =====
    if (tid < 512){
      const int r = tid >> 8, cc = tid & 255;
      float gi = sigm (sG[r][cc]);
      float gf = sigm (sG[r][256+cc]);
      float gg = ftanh(sG[r][512+cc]);
      float go = sigm (sG[r][768+cc]);
      float cn = gf*creg + gi*gg;
      float hn = go*ftanh(cn);
      creg = cn;
      sH[r][cc] = hn;
      enc_out[((size_t)(b0+r)*NT + t)*NH + cc] = f2us(hn);
    } else if (tid < 544 && (t+1) < NT){
      int r = (tid - 512) >> 4, q = tid & 15;
      int idx = sXi[r][t+1];
      *(float4*)&sXe[r][q*4] = *(const float4*)(emb + idx*NE + q*4);
    }
    __syncthreads();
  }

  // ===== final keys[511] (from h_511) + state handoff =====
  if (tid >= 512){
    const int lt = tid - 512;
    const int r = lt >> 8, cc = lt & 255;
    float kv = 0.f;
    const float* wk = WkT + cc;
    #pragma unroll 8
    for (int k = 0; k < NH; ++k) kv += sH[r][k] * wk[(size_t)k*256];
    keys_n[((size_t)(b0 + r)*NT + (NT-1))*NH + cc] = f2us(kv);
  } else {
    const int r = tid >> 8, cc = tid & 255;
    g_h[(b0+r)*NH + cc] = sH[r][cc];
    g_c[(b0+r)*NH + cc] = creg;
  }
}

// ---------------- decoder: ONE batch row per WG, 1024 threads, WG-local, no global sync ----------------
__global__ __launch_bounds__(1024, 1)
void dec_kernel(const int* __restrict__ x, const float* __restrict__ emb,
                const unsigned short* __restrict__ WqT, const float* __restrict__ vvec,
                const unsigned short* __restrict__ WihT, const unsigned short* __restrict__ WhhT,
                const float* __restrict__ bih, const float* __restrict__ bhh,
                const unsigned short* __restrict__ WfcT, const float* __restrict__ bfc,
                const unsigned short* __restrict__ enc_out, const unsigned short* __restrict__ keys_t,
                const float* __restrict__ g_h, const float* __restrict__ g_c,
                float* __restrict__ logits, float* __restrict__ out_h, float* __restrict__ out_c)
{
  const int tid = threadIdx.x;
  const int b   = blockIdx.x;           // this WG's batch row

  __shared__ float sTMP[4096];          // 16KB scratch (partials)
  __shared__ float sWp[512];            // softmax numerators
  __shared__ float sRed[8];
  __shared__ float sQ[256];
  __shared__ float sH[256];
  __shared__ float sCtx[256];
  __shared__ float sXe[64];
  __shared__ float sG[1024];
  __shared__ float sBiasD[1024];
  __shared__ float sBfc[128];
  __shared__ float sV[256];
  __shared__ uint8_t sXi[512];

  // ---- init ----
  sBiasD[tid] = bih[tid] + bhh[tid];
  if (tid < 128) sBfc[tid] = bfc[tid];
  if (tid < 256){ sV[tid] = vvec[tid]; sH[tid] = g_h[b*NH + tid]; }
  if (tid < 512) sXi[tid] = (uint8_t)x[b*NT + tid];
  float creg = (tid < 256) ? g_c[b*NH + tid] : 0.f;
  float hl = 0.f;
  __syncthreads();

  for (int t = 0; t < NT; ++t){
    // ===== S0: q-proj partials (0-511) + logits partials for h_{t-1} (512-1023) =====
    if (tid < 512){
      const int c2 = (tid & 127)*2, kq = tid >> 7;       // 4 k-chunks of 64
      float a0 = 0.f, a1 = 0.f;
      const unsigned short* wp = WqT + (size_t)(kq*64)*256 + c2;
      #pragma unroll 8
      for (int k = 0; k < 64; ++k){
        unsigned u = *(const unsigned*)(wp + (size_t)k*256);
        float a = sH[kq*64 + k];
        a0 += a*lo_bf(u); a1 += a*hi_bf(u);
      }
      sTMP[kq*256 + c2] = a0; sTMP[kq*256 + c2 + 1] = a1;
    } else {
      const int lt = tid - 512;
      const int v2 = (lt & 63)*2, k8 = lt >> 6;          // 8 k-chunks of 32
      float a0 = 0.f, a1 = 0.f;
      const unsigned short* wp = WfcT + (size_t)(k8*32)*128 + v2;
      #pragma unroll 8
      for (int k = 0; k < 32; ++k){
        unsigned u = *(const unsigned*)(wp + (size_t)k*128);
        float a = sH[k8*32 + k];
        a0 += a*lo_bf(u); a1 += a*hi_bf(u);
      }
      sTMP[1024 + k8*128 + v2] = a0; sTMP[1024 + k8*128 + v2 + 1] = a1;
    }
    __syncthreads();
    // ===== S1: combine q; write logits[t-1]; gather emb_t =====
    if (tid < 256){
      sQ[tid] = sTMP[tid] + sTMP[256 + tid] + sTMP[512 + tid] + sTMP[768 + tid];
    } else if (tid >= 512 && tid < 640){
      if (t > 0){
        int vc = tid - 512;
        float lv = sBfc[vc];
        #pragma unroll
        for (int p = 0; p < 8; ++p) lv += sTMP[1024 + p*128 + vc];
        logits[((size_t)b*NT + (t-1))*NV + vc] = lv;
      }
    } else if (tid >= 448 && tid < 512){
      int l = tid - 448;
      sXe[l] = emb[(int)sXi[t]*NE + l];
    }
    __syncthreads();
    // ===== S2: energy partials — keys_t[b][k][t] coalesced along T =====
    {
      const int kh = tid >> 7;        // 8 k-chunks of 32
      const int sp = tid & 127;       // 4 positions each
      const unsigned short* ktp = keys_t + ((size_t)b*NH + kh*32)*NT + sp*4;
      float e0=0.f, e1=0.f, e2=0.f, e3=0.f;
      #pragma unroll 8
      for (int kk = 0; kk < 32; ++kk){
        uint2 u = *(const uint2*)(ktp + (size_t)kk*NT);
        float qk = sQ[kh*32 + kk], vk = sV[kh*32 + kk];
        e0 += vk*ftanh(qk + lo_bf(u.x));
        e1 += vk*ftanh(qk + hi_bf(u.x));
        e2 += vk*ftanh(qk + lo_bf(u.y));
        e3 += vk*ftanh(qk + hi_bf(u.y));
      }
      *(float4*)(sTMP + kh*512 + sp*4) = make_float4(e0,e1,e2,e3);
    }
    __syncthreads();
    // ===== S3: combine energies, mask, exp, per-wave denom partials =====
    if (tid < 512){
      float e = sTMP[tid]      + sTMP[512+tid]  + sTMP[1024+tid] + sTMP[1536+tid]
              + sTMP[2048+tid] + sTMP[2560+tid] + sTMP[3072+tid] + sTMP[3584+tid];
      float w = (sXi[tid] == 0) ? 0.f : __expf(e);
      sWp[tid] = w;
      float s = w;
      #pragma unroll
      for (int off = 32; off > 0; off >>= 1) s += __shfl_down(s, off, 64);
      if ((tid & 63) == 0) sRed[tid >> 6] = s;
    }
    __syncthreads();
    // ===== S4: context partials — enc_out[b][t][h] coalesced along H =====
    {
      const int sc = tid >> 6;        // 16 s-chunks of 32
      const int kc = tid & 63;        // 4 cols each
      const unsigned short* ep = enc_out + ((size_t)b*NT + sc*32)*NH + kc*4;
      float a0=0.f, a1=0.f, a2=0.f, a3=0.f;
      #pragma unroll 8
      for (int ss = 0; ss < 32; ++ss){
        float w = sWp[sc*32 + ss];
        uint2 u = *(const uint2*)(ep + (size_t)ss*NH);
        a0 += w*lo_bf(u.x); a1 += w*hi_bf(u.x);
        a2 += w*lo_bf(u.y); a3 += w*hi_bf(u.y);
      }
      *(float4*)(sTMP + sc*256 + kc*4) = make_float4(a0,a1,a2,a3);
    }
    __syncthreads();
    // ===== S5: combine context =====
    if (tid < 256){
      float den = sRed[0]+sRed[1]+sRed[2]+sRed[3]+sRed[4]+sRed[5]+sRed[6]+sRed[7];
      float rden = (den > 0.f) ? (1.f/den) : 0.f;
      float cs = 0.f;
      #pragma unroll
      for (int p = 0; p < 16; ++p) cs += sTMP[p*256 + tid];
      sCtx[tid] = cs * rden;
    }
    __syncthreads();
    // ===== S6: gate partials — 2 k-segments x 512 gate-pairs, coalesced along G =====
    {
      const int kseg = tid >> 9;            // 0 or 1 (wave-uniform)
      const int g2 = (tid & 511)*2;
      float a0 = 0.f, a1 = 0.f;
      if (kseg == 0){
        const unsigned short* wi = WihT + g2;
        #pragma unroll 8
        for (int k = 0; k < 64; ++k){
          unsigned u = *(const unsigned*)(wi + (size_t)k*1024);
          float a = sXe[k];
          a0 += a*lo_bf(u); a1 += a*hi_bf(u);
        }
        const unsigned short* wc = WihT + (size_t)64*1024 + g2;
        #pragma unroll 8
        for (int k = 0; k < 224; ++k){
          unsigned u = *(const unsigned*)(wc + (size_t)k*1024);
          float a = sCtx[k];
          a0 += a*lo_bf(u); a1 += a*hi_bf(u);
        }
      } else {
        const unsigned short* wc = WihT + (size_t)(64+224)*1024 + g2;
        #pragma unroll 8
        for (int k = 0; k < 32; ++k){
          unsigned u = *(const unsigned*)(wc + (size_t)k*1024);
          float a = sCtx[224 + k];
          a0 += a*lo_bf(u); a1 += a*hi_bf(u);
        }
        const unsigned short* wh = WhhT + g2;
        #pragma unroll 8
        for (int k = 0; k < 256; ++k){
          unsigned u = *(const unsigned*)(wh + (size_t)k*1024);
          float a = sH[k];
          a0 += a*lo_bf(u); a1 += a*hi_bf(u);
        }
      }
      sTMP[kseg*1024 + g2] = a0;
      sTMP[kseg*1024 + g2 + 1] = a1;
    }
    __syncthreads();
    // ===== S6b: combine gates =====
    if (tid < 512){
      const int g2 = tid*2;
      sG[g2]   = sBiasD[g2]   + sTMP[g2]   + sTMP[1024 + g2];
      sG[g2+1] = sBiasD[g2+1] + sTMP[g2+1] + sTMP[1024 + g2 + 1];
    }
    __syncthreads();
    // ===== S7: cell update =====
    if (tid < 256){
      float gi = sigm (sG[tid]);
      float gf = sigm (sG[256 + tid]);
      float gg = ftanh(sG[512 + tid]);
      float go = sigm (sG[768 + tid]);
      float cn = gf*creg + gi*gg;
      float hn = go*ftanh(cn);
      creg = cn; hl = hn;
      sH[tid] = hn;
    }
    __syncthreads();
  }

  // ===== final logits (h_511) + h_f, c_f =====
  if (tid >= 512){
    const int lt = tid - 512;
    const int v2 = (lt & 63)*2, k8 = lt >> 6;
    float a0 = 0.f, a1 = 0.f;
    const unsigned short* wp = WfcT + (size_t)(k8*32)*128 + v2;
    #pragma unroll 8
    for (int k = 0; k < 32; ++k){
      unsigned u = *(const unsigned*)(wp + (size_t)k*128);
      float a = sH[k8*32 + k];
      a0 += a*lo_bf(u); a1 += a*hi_bf(u);
    }
    sTMP[1024 + k8*128 + v2] = a0; sTMP[1024 + k8*128 + v2 + 1] = a1;
  }
  __syncthreads();
  if (tid >= 512 && tid < 640){
    int vc = tid - 512;
    float lv = sBfc[vc];
    #pragma unroll
    for (int p = 0; p < 8; ++p) lv += sTMP[1024 + p*128 + vc];
    logits[((size_t)b*NT + (NT-1))*NV + vc] = lv;
  }
  if (tid < 256){
    out_h[b*NH + tid] = hl;
    out_c[b*NH + tid] = creg;
  }
}

// ---------------- launcher ----------------
extern "C" void kernel_launch(void* const* d_in, const int* in_sizes, int n_in,
                              void* d_out, int out_size, void* d_ws, size_t ws_size,
                              hipStream_t stream)
{
  (void)in_sizes; (void)n_in; (void)out_size; (void)ws_size;
  const int*   x    = (const int*)  d_in[0];
  const float* emb  = (const float*)d_in[1];
  const float* Wihe = (const float*)d_in[2];
  const float* Whhe = (const float*)d_in[3];
  const float* bihe = (const float*)d_in[4];
  const float* bhhe = (const float*)d_in[5];
  const float* Wq   = (const float*)d_in[6];
  const float* Wk   = (const float*)d_in[7];
  const float* vv   = (const float*)d_in[8];
  const float* Wihd = (const float*)d_in[9];
  const float* Whhd = (const float*)d_in[10];
  const float* bihd = (const float*)d_in[11];
  const float* bhhd = (const float*)d_in[12];
  const float* Wfc  = (const float*)d_in[13];
  const float* bfc  = (const float*)d_in[14];

  char* ws = (char*)d_ws;
  unsigned short* enc   = (unsigned short*)(ws + 8192);              // 64 MB bf16 [B][T][H]
  unsigned short* keysn = (unsigned short*)(ws + 8192 + 67108864);   // 64 MB bf16 [B][T][H]
  char* keyst_b = ws + 8192 + (size_t)2*67108864;
  unsigned short* keyst = (unsigned short*)keyst_b;                  // 64 MB bf16 [B][H][T]
  // encoder f32 weights live in the TAIL of keyst: written by prep, read by enc,
  // clobbered by tr afterwards (re-written by prep on every replay -> deterministic)
  float* WiheT = (float*)(keyst_b + 67108864 - 1572864);             // 64*1024 f32
  float* WhheT = WiheT + 64*1024;                                    // 256*1024 f32
  float* WkTe  = WhheT + 256*1024;                                   // 256*256 f32

  float* g_h  = (float*)(ws + 8192 + (size_t)3*67108864);            // B*H f32 (+spare)
  float* g_c  = g_h + 2*NB*NH;                                       // B*H f32
  unsigned short* WqT  = (unsigned short*)(g_c + NB*NH);             // 256*256 bf16
  unsigned short* WfcT = WqT  + 256*256;                             // 256*128 bf16
  unsigned short* WihT = WfcT + 256*128;                             // 320*1024 bf16
  unsigned short* WhhT = WihT + 320*1024;                            // 256*1024 bf16

  float* out_logits = (float*)d_out;
  float* out_h = out_logits + (size_t)NB*NT*NV;
  float* out_c = out_h + NB*NH;

  prep_kernel<<<dim3(1664), dim3(256), 0, stream>>>(
      Wq, Wfc, Wihd, Whhd, Wihe, Whhe, Wk,
      WqT, WfcT, WihT, WhhT, WiheT, WhheT, WkTe);
  enc_kernel<<<dim3(128), dim3(1024), 0, stream>>>(
      x, emb, WiheT, WhheT, bihe, bhhe, WkTe, enc, keysn, g_h, g_c);
  tr_kernel<<<dim3(8192), dim3(256), 0, stream>>>(keysn, keyst);
  dec_kernel<<<dim3(256), dim3(1024), 0, stream>>>(
      x, emb, WqT, vv, WihT, WhhT, bihd, bhhd, WfcT, bfc,
      enc, keyst, g_h, g_c, out_logits, out_h, out_c);
}

// Round 8
// 25662.933 us; speedup vs baseline: 12.8548x; 1.3560x over previous
//
#include <hip/hip_runtime.h>
#include <hip/hip_bf16.h>
#include <stdint.h>

#define NB 256   // batch
#define NT 512   // time
#define NV 128   // vocab
#define NE 64    // embed
#define NH 256   // hidden

typedef __fp16 h2t __attribute__((ext_vector_type(2)));

// ---------------- helpers ----------------
__device__ __forceinline__ float lo_bf(unsigned u){ return __uint_as_float(u << 16); }
__device__ __forceinline__ float hi_bf(unsigned u){ return __uint_as_float(u & 0xffff0000u); }
__device__ __forceinline__ unsigned short f2us(float f){
  unsigned u = __float_as_uint(f);
  unsigned r = u + 0x7fffu + ((u >> 16) & 1u);
  return (unsigned short)(r >> 16);
}
__device__ __forceinline__ float sigm(float x){
  return __builtin_amdgcn_rcpf(1.f + __expf(-x));
}
__device__ __forceinline__ float ftanh(float xx){
  float a = fabsf(xx);
  a = fminf(a, 9.f);
  float e = __expf(2.f * a);
  float r = __builtin_amdgcn_rcpf(e + 1.f);
  float t = (e - 1.f) * r;
  return copysignf(t, xx);
}
__device__ __forceinline__ unsigned pkf16(float a, float b){
  h2t h = __builtin_amdgcn_cvt_pkrtz(a, b);
  unsigned u; __builtin_memcpy(&u, &h, 4); return u;
}
__device__ __forceinline__ float fdot2(unsigned a, unsigned b, float c){
#if __has_builtin(__builtin_amdgcn_fdot2)
  h2t A, B; __builtin_memcpy(&A, &a, 4); __builtin_memcpy(&B, &b, 4);
  return __builtin_amdgcn_fdot2(A, B, c, false);
#else
  h2t A, B; __builtin_memcpy(&A, &a, 4); __builtin_memcpy(&B, &b, 4);
  return c + (float)A.x*(float)B.x + (float)A.y*(float)B.y;
#endif
}

// ---------------- prep: pack all GEMV weights to f16-pair, k-major, uint2-per-2-pairs ----
// layout P[k2p][C][2] : uint j covers k = 4*k2p+2*j .. +1   (C = out-column count)
__global__ __launch_bounds__(256, 1)
void prep_kernel(const float* __restrict__ Wq, const float* __restrict__ Wfc,
                 const float* __restrict__ Wihd, const float* __restrict__ Whhd,
                 const float* __restrict__ Wihe, const float* __restrict__ Whhe,
                 const float* __restrict__ Wk,
                 unsigned* __restrict__ Wq4, unsigned* __restrict__ Wfc4,
                 unsigned* __restrict__ Wihd4, unsigned* __restrict__ Whhd4,
                 unsigned* __restrict__ Wihe4, unsigned* __restrict__ Whhe4,
                 unsigned* __restrict__ Wke4)
{
  const int blk = blockIdx.x, tid = threadIdx.x;
  if (blk < 64){                        // Wq4: C=256, K=256 -> 64 k2p x 512
    int k2p = blk;
    #pragma unroll
    for (int l = 0; l < 2; ++l){
      int i = l*256 + tid, c = i>>1, j = i&1, k = 4*k2p + 2*j;
      Wq4[k2p*512 + i] = pkf16(Wq[c*256 + k], Wq[c*256 + k + 1]);
    }
  } else if (blk < 128){                // Wfc4: C=128, K=256 -> 64 k2p x 256
    int k2p = blk - 64;
    int c = tid>>1, j = tid&1, k = 4*k2p + 2*j;
    Wfc4[k2p*256 + tid] = pkf16(Wfc[c*256 + k], Wfc[c*256 + k + 1]);
  } else if (blk < 208){                // Wihd4: C=1024, K=320 -> 80 k2p x 2048
    int k2p = blk - 128;
    #pragma unroll
    for (int l = 0; l < 8; ++l){
      int i = l*256 + tid, g = i>>1, j = i&1, k = 4*k2p + 2*j;
      Wihd4[(size_t)k2p*2048 + i] = pkf16(Wihd[g*320 + k], Wihd[g*320 + k + 1]);
    }
  } else if (blk < 272){                // Whhd4: C=1024, K=256 -> 64 k2p x 2048
    int k2p = blk - 208;
    #pragma unroll
    for (int l = 0; l < 8; ++l){
      int i = l*256 + tid, g = i>>1, j = i&1, k = 4*k2p + 2*j;
      Whhd4[(size_t)k2p*2048 + i] = pkf16(Whhd[g*256 + k], Whhd[g*256 + k + 1]);
    }
  } else if (blk < 288){                // Wihe4: C=1024, K=64 -> 16 k2p x 2048
    int k2p = blk - 272;
    #pragma unroll
    for (int l = 0; l < 8; ++l){
      int i = l*256 + tid, g = i>>1, j = i&1, k = 4*k2p + 2*j;
      Wihe4[(size_t)k2p*2048 + i] = pkf16(Wihe[g*64 + k], Wihe[g*64 + k + 1]);
    }
  } else if (blk < 352){                // Whhe4: C=1024, K=256 -> 64 k2p x 2048
    int k2p = blk - 288;
    #pragma unroll
    for (int l = 0; l < 8; ++l){
      int i = l*256 + tid, g = i>>1, j = i&1, k = 4*k2p + 2*j;
      Whhe4[(size_t)k2p*2048 + i] = pkf16(Whhe[g*256 + k], Whhe[g*256 + k + 1]);
    }
  } else {                              // Wke4: C=256, K=256 -> 64 k2p x 512
    int k2p = blk - 352;
    #pragma unroll
    for (int l = 0; l < 2; ++l){
      int i = l*256 + tid, c = i>>1, j = i&1, k = 4*k2p + 2*j;
      Wke4[k2p*512 + i] = pkf16(Wk[c*256 + k], Wk[c*256 + k + 1]);
    }
  }
}

// ---------------- key transpose: keys_n[B][T][H] -> keys_t[B][H][T] ----------------
__global__ __launch_bounds__(256, 1)
void tr_kernel(const unsigned short* __restrict__ keys_n, unsigned short* __restrict__ keys_t)
{
  __shared__ unsigned short tile[64][68];
  const int blk = blockIdx.x, tid = threadIdx.x;
  const int b  = blk >> 5;
  const int tt = (blk >> 2) & 7;
  const int hh = blk & 3;
  const int t0 = tt*64, h0 = hh*64;

  #pragma unroll
  for (int i = 0; i < 4; ++i){
    int idx = tid + i*256;
    int t = idx >> 4, h4 = (idx & 15)*4;
    uint2 u = *(const uint2*)(keys_n + ((size_t)b*NT + t0 + t)*NH + h0 + h4);
    *(uint2*)&tile[t][h4] = u;
  }
  __syncthreads();
  #pragma unroll
  for (int i = 0; i < 4; ++i){
    int idx = tid + i*256;
    int h = idx >> 4, t4 = (idx & 15)*4;
    unsigned short a = tile[t4+0][h], bb = tile[t4+1][h], cc = tile[t4+2][h], dd = tile[t4+3][h];
    uint2 u; u.x = (unsigned)a | ((unsigned)bb << 16); u.y = (unsigned)cc | ((unsigned)dd << 16);
    *(uint2*)(keys_t + ((size_t)b*NH + h0 + h)*NT + t0 + t4) = u;
  }
}

// ---------------- encoder: 2 rows/WG, 1024 threads, dot2 GEMVs, WG-local ----------------
__global__ __launch_bounds__(1024, 1)
void enc_kernel(const int* __restrict__ x, const float* __restrict__ emb,
                const unsigned* __restrict__ Wihe4, const unsigned* __restrict__ Whhe4,
                const float* __restrict__ bih, const float* __restrict__ bhh,
                const unsigned* __restrict__ Wke4,
                unsigned short* __restrict__ enc_out, unsigned short* __restrict__ keys_n,
                float* __restrict__ g_h, float* __restrict__ g_c)
{
  const int tid = threadIdx.x;
  const int b0  = blockIdx.x * 2;

  __shared__ unsigned sH2[2][128];
  __shared__ unsigned sXe2[2][32];
  __shared__ float sG[2][1024];
  __shared__ float sBias[1024];
  __shared__ float sKP[1024];
  __shared__ uint8_t sXi[2][512];

  sBias[tid] = bih[tid] + bhh[tid];
  { int r = tid >> 9; sXi[r][tid & 511] = (uint8_t)x[(b0 + r)*NT + (tid & 511)]; }
  if (tid < 256) sH2[tid>>7][tid&127] = 0u;   // f16 pair (0,0)
  __syncthreads();
  if (tid < 64){
    int r = tid>>5, p = tid&31, idx = sXi[r][0];
    sXe2[r][p] = pkf16(emb[idx*NE + 2*p], emb[idx*NE + 2*p + 1]);
  }
  float creg = 0.f, hl = 0.f;
  __syncthreads();

  for (int t = 0; t < NT; ++t){
    // ===== B: gates (all 1024 threads, 1 gate x 2 rows) + key partials =====
    {
      const int g = tid;
      float a0 = sBias[g], a1 = a0;
      const unsigned* Wi = Wihe4 + g*2;
      #pragma unroll 4
      for (int p = 0; p < 16; ++p){
        uint2 w = *(const uint2*)(Wi + (size_t)p*2048);
        a0 = fdot2(sXe2[0][2*p], w.x, a0); a0 = fdot2(sXe2[0][2*p+1], w.y, a0);
        a1 = fdot2(sXe2[1][2*p], w.x, a1); a1 = fdot2(sXe2[1][2*p+1], w.y, a1);
      }
      const unsigned* Wh = Whhe4 + g*2;
      #pragma unroll 4
      for (int p = 0; p < 64; ++p){
        uint2 w = *(const uint2*)(Wh + (size_t)p*2048);
        a0 = fdot2(sH2[0][2*p], w.x, a0); a0 = fdot2(sH2[0][2*p+1], w.y, a0);
        a1 = fdot2(sH2[1][2*p], w.x, a1); a1 = fdot2(sH2[1][2*p+1], w.y, a1);
      }
      sG[0][g] = a0; sG[1][g] = a1;
    }
    if (t > 0){
      const int r = tid>>9, half = (tid>>8)&1, c = tid&255;
      float kp = 0.f;
      const unsigned* Wk4 = Wke4 + c*2;
      #pragma unroll 4
      for (int p = 0; p < 32; ++p){
        int k2p = half*32 + p;
        uint2 w = *(const uint2*)(Wk4 + k2p*512);
        kp = fdot2(sH2[r][2*k2p], w.x, kp);
        kp = fdot2(sH2[r][2*k2p+1], w.y, kp);
      }
      sKP[tid] = kp;
    }
    __syncthreads();
    // ===== C: cell (0-511) | keys combine+write (512-1023) =====
    if (tid < 512){
      const int r = tid>>8, cc = tid&255;
      float gi = sigm (sG[r][cc]);
      float gf = sigm (sG[r][256+cc]);
      float gg = ftanh(sG[r][512+cc]);
      float go = sigm (sG[r][768+cc]);
      float cn = gf*creg + gi*gg;
      float hn = go*ftanh(cn);
      creg = cn; hl = hn;
      enc_out[((size_t)(b0+r)*NT + t)*NH + cc] = f2us(hn);
      float hb = __shfl_down(hn, 1, 64);
      if (!(cc & 1)) sH2[r][cc>>1] = pkf16(hn, hb);
      if (tid < 64 && (t+1) < NT){
        int r2 = tid>>5, p = tid&31, idx = sXi[r2][t+1];
        sXe2[r2][p] = pkf16(emb[idx*NE + 2*p], emb[idx*NE + 2*p + 1]);
      }
    } else if (t > 0){
      const int r = (tid>>8)&1, c = tid&255;
      float kv = sKP[(r<<9) + c] + sKP[(r<<9) + 256 + c];
      keys_n[((size_t)(b0+r)*NT + (t-1))*NH + c] = f2us(kv);
    }
    __syncthreads();
  }
  // final keys[NT-1] from h_{NT-1}
  {
    const int r = tid>>9, half = (tid>>8)&1, c = tid&255;
    float kp = 0.f;
    const unsigned* Wk4 = Wke4 + c*2;
    #pragma unroll 4
    for (int p = 0; p < 32; ++p){
      int k2p = half*32 + p;
      uint2 w = *(const uint2*)(Wk4 + k2p*512);
      kp = fdot2(sH2[r][2*k2p], w.x, kp);
      kp = fdot2(sH2[r][2*k2p+1], w.y, kp);
    }
    sKP[tid] = kp;
  }
  __syncthreads();
  if (tid >= 512){
    const int r = (tid>>8)&1, c = tid&255;
    float kv = sKP[(r<<9) + c] + sKP[(r<<9) + 256 + c];
    keys_n[((size_t)(b0+r)*NT + (NT-1))*NH + c] = f2us(kv);
  } else {
    const int r = tid>>8, cc = tid&255;
    g_h[(b0+r)*NH + cc] = hl;
    g_c[(b0+r)*NH + cc] = creg;
  }
}

// ---------------- decoder: 1 row/WG, 1024 threads, dot2 GEMVs, no logits in loop ----------------
__global__ __launch_bounds__(1024, 1)
void dec_kernel(const int* __restrict__ x, const float* __restrict__ emb,
                const unsigned* __restrict__ Wq4, const float* __restrict__ vvec,
                const unsigned* __restrict__ Wihd4, const unsigned* __restrict__ Whhd4,
                const float* __restrict__ bih, const float* __restrict__ bhh,
                const unsigned short* __restrict__ enc_out, const unsigned short* __restrict__ keys_t,
                const float* __restrict__ g_h, const float* __restrict__ g_c,
                unsigned* __restrict__ h2_hist, float* __restrict__ out_h, float* __restrict__ out_c)
{
  const int tid = threadIdx.x;
  const int b   = blockIdx.x;

  __shared__ float sTMP[4096];
  __shared__ float sWp[512];
  __shared__ float sRed[8];
  __shared__ float sQ2[256];        // 2*log2(e) * q
  __shared__ unsigned sH2[128];
  __shared__ unsigned sCtx2[128];
  __shared__ unsigned sXe2[32];
  __shared__ float sG[1024];
  __shared__ float sBiasD[1024];
  __shared__ float sVm2[256];       // -2*v
  __shared__ float sVs[8];          // per-32k-chunk sum of v
  __shared__ uint8_t sXi[512];

  sBiasD[tid] = bih[tid] + bhh[tid];
  if (tid < 256) sVm2[tid] = -2.f * vvec[tid];
  if (tid < 512) sXi[tid] = (uint8_t)x[b*NT + tid];
  if (tid < 128) sH2[tid] = pkf16(g_h[b*NH + 2*tid], g_h[b*NH + 2*tid + 1]);
  if (tid < 8){
    float s = 0.f;
    #pragma unroll
    for (int j = 0; j < 32; ++j) s += vvec[tid*32 + j];
    sVs[tid] = s;
  }
  float creg = (tid < 256) ? g_c[b*NH + tid] : 0.f;
  float hl = 0.f;
  const float CLN = 2.885390081777927f;   // 2*log2(e)
  __syncthreads();

  for (int t = 0; t < NT; ++t){
    // ===== S0: q-proj partials, 4 k-chunks x 256 cols =====
    {
      const int c = tid & 255, kq = tid >> 8;
      float a = 0.f;
      const unsigned* Wp = Wq4 + c*2;
      #pragma unroll 4
      for (int p = 0; p < 16; ++p){
        int k2p = kq*16 + p;
        uint2 w = *(const uint2*)(Wp + k2p*512);
        a = fdot2(sH2[2*k2p], w.x, a);
        a = fdot2(sH2[2*k2p+1], w.y, a);
      }
      sTMP[kq*256 + c] = a;
    }
    __syncthreads();
    // ===== S1: combine q (pre-scaled), gather+pack emb_t =====
    if (tid < 256){
      float qv = sTMP[tid] + sTMP[256 + tid] + sTMP[512 + tid] + sTMP[768 + tid];
      sQ2[tid] = CLN * qv;
    } else if (tid < 288){
      int p = tid - 256, idx = sXi[t];
      sXe2[p] = pkf16(emb[idx*NE + 2*p], emb[idx*NE + 2*p + 1]);
    }
    __syncthreads();
    // ===== S2: energy partials (cheap tanh: 1-2/(1+exp2(C*x)), v folded) =====
    {
      const int kh = tid >> 7, sp = tid & 127;
      const unsigned short* ktp = keys_t + ((size_t)b*NH + kh*32)*NT + sp*4;
      float e0 = sVs[kh], e1 = e0, e2 = e0, e3 = e0;
      #pragma unroll 4
      for (int kk = 0; kk < 32; ++kk){
        uint2 u = *(const uint2*)(ktp + (size_t)kk*NT);
        float q2 = sQ2[kh*32 + kk];
        float vm = sVm2[kh*32 + kk];
        float r0 = __builtin_amdgcn_rcpf(1.f + exp2f(fmaf(CLN, lo_bf(u.x), q2)));
        float r1 = __builtin_amdgcn_rcpf(1.f + exp2f(fmaf(CLN, hi_bf(u.x), q2)));
        float r2 = __builtin_amdgcn_rcpf(1.f + exp2f(fmaf(CLN, lo_bf(u.y), q2)));
        float r3 = __builtin_amdgcn_rcpf(1.f + exp2f(fmaf(CLN, hi_bf(u.y), q2)));
        e0 = fmaf(vm, r0, e0); e1 = fmaf(vm, r1, e1);
        e2 = fmaf(vm, r2, e2); e3 = fmaf(vm, r3, e3);
      }
      *(float4*)(sTMP + kh*512 + sp*4) = make_float4(e0,e1,e2,e3);
    }
    __syncthreads();
    // ===== S3: combine energies, mask, exp, per-wave denom partials =====
    if (tid < 512){
      float e = sTMP[tid]      + sTMP[512+tid]  + sTMP[1024+tid] + sTMP[1536+tid]
              + sTMP[2048+tid] + sTMP[2560+tid] + sTMP[3072+tid] + sTMP[3584+tid];
      float w = (sXi[tid] == 0) ? 0.f : __expf(e);
      sWp[tid] = w;
      float s = w;
      #pragma unroll
      for (int off = 32; off > 0; off >>= 1) s += __shfl_down(s, off, 64);
      if ((tid & 63) == 0) sRed[tid >> 6] = s;
    }
    __syncthreads();
    // ===== S4: context partials — enc_out[b][t][h] coalesced along H =====
    {
      const int sc = tid >> 6;
      const int kc = tid & 63;
      const unsigned short* ep = enc_out + ((size_t)b*NT + sc*32)*NH + kc*4;
      float a0=0.f, a1=0.f, a2=0.f, a3=0.f;
      #pragma unroll 8
      for (int ss = 0; ss < 32; ++ss){
        float w = sWp[sc*32 + ss];
        uint2 u = *(const uint2*)(ep + (size_t)ss*NH);
        a0 += w*lo_bf(u.x); a1 += w*hi_bf(u.x);
        a2 += w*lo_bf(u.y); a3 += w*hi_bf(u.y);
      }
      *(float4*)(sTMP + sc*256 + kc*4) = make_float4(a0,a1,a2,a3);
    }
    __syncthreads();
    // ===== S5: combine context + pack f16 pairs =====
    if (tid < 256){
      float den = sRed[0]+sRed[1]+sRed[2]+sRed[3]+sRed[4]+sRed[5]+sRed[6]+sRed[7];
      float rden = (den > 0.f) ? (1.f/den) : 0.f;
      float cs = 0.f;
      #pragma unroll
      for (int p = 0; p < 16; ++p) cs += sTMP[p*256 + tid];
      float cv = cs * rden;
      float cb = __shfl_down(cv, 1, 64);
      if (!(tid & 1)) sCtx2[tid>>1] = pkf16(cv, cb);
    }
    __syncthreads();
    // ===== S6: gates — 1 gate per thread, dot2, direct write =====
    {
      const int g = tid;
      float a = sBiasD[g];
      const unsigned* Wi = Wihd4 + g*2;
      #pragma unroll 4
      for (int p = 0; p < 16; ++p){
        uint2 w = *(const uint2*)(Wi + (size_t)p*2048);
        a = fdot2(sXe2[2*p], w.x, a); a = fdot2(sXe2[2*p+1], w.y, a);
      }
      #pragma unroll 4
      for (int p = 0; p < 64; ++p){
        uint2 w = *(const uint2*)(Wi + (size_t)(16+p)*2048);
        a = fdot2(sCtx2[2*p], w.x, a); a = fdot2(sCtx2[2*p+1], w.y, a);
      }
      const unsigned* Wh = Whhd4 + g*2;
      #pragma unroll 4
      for (int p = 0; p < 64; ++p){
        uint2 w = *(const uint2*)(Wh + (size_t)p*2048);
        a = fdot2(sH2[2*p], w.x, a); a = fdot2(sH2[2*p+1], w.y, a);
      }
      sG[g] = a;
    }
    __syncthreads();
    // ===== S7: cell update + pack h + h-history dump =====
    if (tid < 256){
      float gi = sigm (sG[tid]);
      float gf = sigm (sG[256 + tid]);
      float gg = ftanh(sG[512 + tid]);
      float go = sigm (sG[768 + tid]);
      float cn = gf*creg + gi*gg;
      float hn = go*ftanh(cn);
      creg = cn; hl = hn;
      float hb = __shfl_down(hn, 1, 64);
      if (!(tid & 1)){
        unsigned hp = pkf16(hn, hb);
        sH2[tid>>1] = hp;
        h2_hist[((size_t)b*NT + t)*128 + (tid>>1)] = hp;
      }
    }
    __syncthreads();
  }

  if (tid < 256){
    out_h[b*NH + tid] = hl;
    out_c[b*NH + tid] = creg;
  }
}

// ---------------- fc: logits = h_hist @ Wfc^T + bfc  (8 rows per block) ----------------
__global__ __launch_bounds__(256, 1)
void fc_kernel(const unsigned* __restrict__ h2_hist, const unsigned* __restrict__ Wfc4,
               const float* __restrict__ bfc, float* __restrict__ logits)
{
  __shared__ unsigned sHH[1024];     // 8 rows x 128 pairs
  const int tid = threadIdx.x;
  const size_t row0 = (size_t)blockIdx.x * 8;
  #pragma unroll
  for (int l = 0; l < 4; ++l) sHH[l*256 + tid] = h2_hist[row0*128 + l*256 + tid];
  __syncthreads();
  const int r = tid >> 7, v = tid & 127;
  float bv = bfc[v];
  float a0 = bv, a1 = bv, a2 = bv, a3 = bv;
  const unsigned* Wp = Wfc4 + v*2;
  #pragma unroll 4
  for (int k2p = 0; k2p < 64; ++k2p){
    uint2 w = *(const uint2*)(Wp + k2p*256);
    int k2 = 2*k2p;
    a0 = fdot2(sHH[(r  )*128 + k2], w.x, a0); a0 = fdot2(sHH[(r  )*128 + k2+1], w.y, a0);
    a1 = fdot2(sHH[(r+2)*128 + k2], w.x, a1); a1 = fdot2(sHH[(r+2)*128 + k2+1], w.y, a1);
    a2 = fdot2(sHH[(r+4)*128 + k2], w.x, a2); a2 = fdot2(sHH[(r+4)*128 + k2+1], w.y, a2);
    a3 = fdot2(sHH[(r+6)*128 + k2], w.x, a3); a3 = fdot2(sHH[(r+6)*128 + k2+1], w.y, a3);
  }
  logits[(row0 + r    )*NV + v] = a0;
  logits[(row0 + r + 2)*NV + v] = a1;
  logits[(row0 + r + 4)*NV + v] = a2;
  logits[(row0 + r + 6)*NV + v] = a3;
}

// ---------------- launcher ----------------
extern "C" void kernel_launch(void* const* d_in, const int* in_sizes, int n_in,
                              void* d_out, int out_size, void* d_ws, size_t ws_size,
                              hipStream_t stream)
{
  (void)in_sizes; (void)n_in; (void)out_size; (void)ws_size;
  const int*   x    = (const int*)  d_in[0];
  const float* emb  = (const float*)d_in[1];
  const float* Wihe = (const float*)d_in[2];
  const float* Whhe = (const float*)d_in[3];
  const float* bihe = (const float*)d_in[4];
  const float* bhhe = (const float*)d_in[5];
  const float* Wq   = (const float*)d_in[6];
  const float* Wk   = (const float*)d_in[7];
  const float* vv   = (const float*)d_in[8];
  const float* Wihd = (const float*)d_in[9];
  const float* Whhd = (const float*)d_in[10];
  const float* bihd = (const float*)d_in[11];
  const float* bhhd = (const float*)d_in[12];
  const float* Wfc  = (const float*)d_in[13];
  const float* bfc  = (const float*)d_in[14];

  char* ws = (char*)d_ws;
  const size_t M64 = 67108864;
  unsigned short* enc   = (unsigned short*)(ws);           // 64 MB bf16 [B][T][H]
  unsigned short* keysn = (unsigned short*)(ws + M64);     // 64 MB bf16 [B][T][H]; later reused as h2_hist
  unsigned short* keyst = (unsigned short*)(ws + 2*M64);   // 64 MB bf16 [B][H][T]
  unsigned* h2_hist     = (unsigned*)(ws + M64);           // overlays keysn (dead after tr)
  float* g_h = (float*)(ws + 3*M64);                       // 256 KB
  float* g_c = g_h + NB*NH;
  unsigned* Wq4   = (unsigned*)(g_c + NB*NH);              // 64*512
  unsigned* Wfc4  = Wq4   + 64*512;                        // 64*256
  unsigned* Wihd4 = Wfc4  + 64*256;                        // 80*2048
  unsigned* Whhd4 = Wihd4 + 80*2048;                       // 64*2048
  unsigned* Wihe4 = Whhd4 + 64*2048;                       // 16*2048
  unsigned* Whhe4 = Wihe4 + 16*2048;                       // 64*2048
  unsigned* Wke4  = Whhe4 + 64*2048;                       // 64*512

  float* out_logits = (float*)d_out;
  float* out_h = out_logits + (size_t)NB*NT*NV;
  float* out_c = out_h + NB*NH;

  prep_kernel<<<dim3(416), dim3(256), 0, stream>>>(
      Wq, Wfc, Wihd, Whhd, Wihe, Whhe, Wk,
      Wq4, Wfc4, Wihd4, Whhd4, Wihe4, Whhe4, Wke4);
  enc_kernel<<<dim3(128), dim3(1024), 0, stream>>>(
      x, emb, Wihe4, Whhe4, bihe, bhhe, Wke4, enc, keysn, g_h, g_c);
  tr_kernel<<<dim3(8192), dim3(256), 0, stream>>>(keysn, keyst);
  dec_kernel<<<dim3(256), dim3(1024), 0, stream>>>(
      x, emb, Wq4, vv, Wihd4, Whhd4, bihd, bhhd,
      enc, keyst, g_h, g_c, h2_hist, out_h, out_c);
  fc_kernel<<<dim3(16384), dim3(256), 0, stream>>>(h2_hist, Wfc4, bfc, out_logits);
}